// Round 1
// baseline (1623.402 us; speedup 1.0000x reference)
//
#include <hip/hip_runtime.h>
#include <math.h>

constexpr int NN   = 20000;
constexpr int EE   = 320000;
constexpr int ET   = EE + NN;   // 340000 with self loops
constexpr int GG   = 128;
constexpr int DEE  = 64;
constexpr int DD   = 512;
constexpr int OUTD = 256;

// ---------------- embedding gather ----------------
__global__ __launch_bounds__(256) void k_embed(const int* __restrict__ ids,
                                               const float* __restrict__ emb,
                                               float* __restrict__ x0) {
  for (int i = blockIdx.x * 256 + threadIdx.x; i < NN * DEE; i += gridDim.x * 256) {
    int n = i >> 6, d = i & 63;
    x0[i] = emb[ids[n] * DEE + d];
  }
}

// ---------------- graph node-count histogram ----------------
__global__ __launch_bounds__(256) void k_gcnt(const int* __restrict__ batch, int* __restrict__ gcnt) {
  for (int n = blockIdx.x * 256 + threadIdx.x; n < NN; n += gridDim.x * 256)
    atomicAdd(&gcnt[batch[n]], 1);
}

// ---------------- CSR build ----------------
__global__ __launch_bounds__(256) void k_count(const int* __restrict__ ei, int* __restrict__ cnt) {
  for (int k = blockIdx.x * 256 + threadIdx.x; k < ET; k += gridDim.x * 256) {
    int d = (k < EE) ? ei[EE + k] : (k - EE);
    atomicAdd(&cnt[d], 1);
  }
}

__global__ __launch_bounds__(1024) void k_scan(const int* __restrict__ cnt, int* __restrict__ off) {
  __shared__ int part[1024];
  int tid = threadIdx.x;
  constexpr int CH = (NN + 1023) / 1024;  // 20
  int base = tid * CH;
  int s = 0;
  for (int i = 0; i < CH; ++i) { int idx = base + i; if (idx < NN) s += cnt[idx]; }
  part[tid] = s;
  __syncthreads();
  for (int o = 1; o < 1024; o <<= 1) {
    int add = (tid >= o) ? part[tid - o] : 0;
    int v = part[tid];
    __syncthreads();
    part[tid] = v + add;
    __syncthreads();
  }
  int run = (tid == 0) ? 0 : part[tid - 1];
  for (int i = 0; i < CH; ++i) {
    int idx = base + i;
    if (idx < NN) { off[idx] = run; run += cnt[idx]; }
  }
  if (tid == 1023) off[NN] = ET;
}

__global__ __launch_bounds__(256) void k_scatter(const int* __restrict__ ei, const int* __restrict__ off,
                                                 int* __restrict__ cur, int* __restrict__ csrc) {
  for (int k = blockIdx.x * 256 + threadIdx.x; k < ET; k += gridDim.x * 256) {
    int s = (k < EE) ? ei[k]      : (k - EE);
    int d = (k < EE) ? ei[EE + k] : (k - EE);
    int p = atomicAdd(&cur[d], 1);
    csrc[off[d] + p] = s;
  }
}

// ---------------- fp32 tiled GEMM: C[M,Nc] = A[M,K] @ B[K,Nc] ----------------
// mode: 0 = plain, 1 = +bias, 2 = +bias then exact GELU
__global__ __launch_bounds__(256) void k_gemm(const float* __restrict__ A, const float* __restrict__ B,
                                              float* __restrict__ Cout, const float* __restrict__ bias,
                                              int M, int Nc, int K, int mode) {
  __shared__ float As[16][68];
  __shared__ float Bs[16][68];
  int tid = threadIdx.x;
  int m0 = blockIdx.x * 64, n0 = blockIdx.y * 64;
  int tx = tid & 15, ty = tid >> 4;
  int lam = tid >> 2, lak = (tid & 3) * 4;   // A-tile load: row lam (0..63), k sub 4
  int lbk = tid >> 4, lbn = (tid & 15) * 4;  // B-tile load: k row (0..15), 4 cols
  float acc[4][4] = {};
  int ar = m0 + lam;
  for (int k0 = 0; k0 < K; k0 += 16) {
    float4 av;
    if (ar < M) av = *(const float4*)(A + (size_t)ar * K + k0 + lak);
    else        av = make_float4(0.f, 0.f, 0.f, 0.f);
    As[lak + 0][lam] = av.x; As[lak + 1][lam] = av.y;
    As[lak + 2][lam] = av.z; As[lak + 3][lam] = av.w;
    *(float4*)&Bs[lbk][lbn] = *(const float4*)(B + (size_t)(k0 + lbk) * Nc + n0 + lbn);
    __syncthreads();
#pragma unroll
    for (int kk = 0; kk < 16; ++kk) {
      const float4 a4 = *(const float4*)&As[kk][ty << 2];
      const float4 b4 = *(const float4*)&Bs[kk][tx << 2];
      const float a[4] = {a4.x, a4.y, a4.z, a4.w};
      const float b[4] = {b4.x, b4.y, b4.z, b4.w};
#pragma unroll
      for (int i = 0; i < 4; ++i)
#pragma unroll
        for (int j = 0; j < 4; ++j)
          acc[i][j] = fmaf(a[i], b[j], acc[i][j]);
    }
    __syncthreads();
  }
#pragma unroll
  for (int i = 0; i < 4; ++i) {
    int row = m0 + ty * 4 + i;
    if (row >= M) continue;
#pragma unroll
    for (int j = 0; j < 4; ++j) {
      int col = n0 + tx * 4 + j;
      float v = acc[i][j];
      if (mode >= 1) v += bias[col];
      if (mode == 2) v = 0.5f * v * (1.0f + erff(v * 0.70710678118654752f));
      Cout[(size_t)row * Nc + col] = v;
    }
  }
}

// ---------------- attention score dots: s_src/s_dst [N,4] ----------------
__global__ __launch_bounds__(256) void k_sdots(const float* __restrict__ xp,
                                               const float* __restrict__ asw,
                                               const float* __restrict__ adw,
                                               float* __restrict__ ssrc, float* __restrict__ sdst) {
  int n = blockIdx.x;
  int t = threadIdx.x;
  int h = t >> 6;      // head = wave id
  int l = t & 63;
  const float* row = xp + (size_t)n * DD + h * 128;
  float a = 0.f, b = 0.f;
  for (int c = l; c < 128; c += 64) {
    float v = row[c];
    a += v * asw[h * 128 + c];
    b += v * adw[h * 128 + c];
  }
#pragma unroll
  for (int o = 32; o; o >>= 1) { a += __shfl_down(a, o); b += __shfl_down(b, o); }
  if (l == 0) { ssrc[n * 4 + h] = a; sdst[n * 4 + h] = b; }
}

// ---------------- per-node edge-softmax aggregation (+bias+residual, LN partials) ----------------
__global__ __launch_bounds__(256) void k_agg(const float* __restrict__ xp,
                                             const float* __restrict__ ssrc,
                                             const float* __restrict__ sdst,
                                             const int* __restrict__ off,
                                             const int* __restrict__ csr,
                                             const int* __restrict__ batch,
                                             const float* __restrict__ bias,
                                             float* __restrict__ xio,   // in: residual, out: pre-LN
                                             float* __restrict__ gsum, float* __restrict__ gsq) {
  int n = blockIdx.x;
  int tid = threadIdx.x;
  int wv = tid >> 6, ln = tid & 63;
  int beg = off[n], end = off[n + 1];

  __shared__ float sd[4], fm[4], fden[4];
  __shared__ float redm[4][4], reds[4][4];
  __shared__ int   lsrc[64];
  __shared__ float lw[64][4];
  __shared__ float rs[4], rq[4];

  if (tid < 4) sd[tid] = sdst[n * 4 + tid];
  __syncthreads();

  // ---- stage 1: online softmax stats per head ----
  float m[4] = {-INFINITY, -INFINITY, -INFINITY, -INFINITY};
  float s[4] = {0.f, 0.f, 0.f, 0.f};
  for (int k = beg + tid; k < end; k += 256) {
    int sk = csr[k];
    float4 sv = *(const float4*)(ssrc + (size_t)sk * 4);
    float ev[4] = {sv.x, sv.y, sv.z, sv.w};
#pragma unroll
    for (int h = 0; h < 4; ++h) {
      float e = ev[h] + sd[h];
      e = (e > 0.f) ? e : 0.2f * e;
      if (e > m[h]) { s[h] = s[h] * expf(m[h] - e) + 1.0f; m[h] = e; }
      else          { s[h] += expf(e - m[h]); }
    }
  }
#pragma unroll
  for (int o = 32; o; o >>= 1) {
#pragma unroll
    for (int h = 0; h < 4; ++h) {
      float om = __shfl_xor(m[h], o);
      float os = __shfl_xor(s[h], o);
      float M = fmaxf(m[h], om);
      if (M > -1e37f) {
        s[h] = s[h] * expf(m[h] - M) + os * expf(om - M);
        m[h] = M;
      }
    }
  }
  if (ln == 0) {
#pragma unroll
    for (int h = 0; h < 4; ++h) { redm[wv][h] = m[h]; reds[wv][h] = s[h]; }
  }
  __syncthreads();
  if (tid < 4) {
    float M = -INFINITY, S = 0.f;
    for (int w = 0; w < 4; ++w) {
      float om = redm[w][tid], os = reds[w][tid];
      float Mn = fmaxf(M, om);
      if (Mn > -1e37f) { S = S * expf(M - Mn) + os * expf(om - Mn); M = Mn; }
    }
    fm[tid] = M; fden[tid] = S;
  }
  __syncthreads();

  // ---- stage 2: weighted accumulation, chunks of 64 edges ----
  int d0 = tid, d1 = tid + 256;
  int h0 = d0 >> 7, h1 = d1 >> 7;
  float acc0 = 0.f, acc1 = 0.f;
  int kk_ = tid >> 2, hh = tid & 3;
  for (int kb = beg; kb < end; kb += 64) {
    int cnt = min(64, end - kb);
    if (tid < cnt) lsrc[tid] = csr[kb + tid];
    __syncthreads();
    if (kk_ < cnt) {
      int sk = lsrc[kk_];
      float e = ssrc[(size_t)sk * 4 + hh] + sd[hh];
      e = (e > 0.f) ? e : 0.2f * e;
      lw[kk_][hh] = expf(e - fm[hh]);
    }
    __syncthreads();
    for (int kk = 0; kk < cnt; ++kk) {
      int sk = lsrc[kk];
      const float* xr = xp + (size_t)sk * DD;
      acc0 += lw[kk][h0] * xr[d0];
      acc1 += lw[kk][h1] * xr[d1];
    }
    __syncthreads();
  }
  float o0 = acc0 / fden[h0] + bias[d0] + xio[(size_t)n * DD + d0];
  float o1 = acc1 / fden[h1] + bias[d1] + xio[(size_t)n * DD + d1];
  xio[(size_t)n * DD + d0] = o0;
  xio[(size_t)n * DD + d1] = o1;

  // ---- LN partial sums for this node ----
  float ps = o0 + o1;
  float pq = o0 * o0 + o1 * o1;
#pragma unroll
  for (int o = 32; o; o >>= 1) { ps += __shfl_xor(ps, o); pq += __shfl_xor(pq, o); }
  if (ln == 0) { rs[wv] = ps; rq[wv] = pq; }
  __syncthreads();
  if (tid == 0) {
    float S = rs[0] + rs[1] + rs[2] + rs[3];
    float Q = rq[0] + rq[1] + rq[2] + rq[3];
    int g = batch[n];
    atomicAdd(&gsum[g], S);
    atomicAdd(&gsq[g], Q);
  }
}

// ---------------- per-graph LN stats ----------------
__global__ void k_stats(const int* __restrict__ gcnt, const float* __restrict__ gsum,
                        const float* __restrict__ gsq, float* __restrict__ gmu, float* __restrict__ grstd) {
  int t = threadIdx.x;
  if (t < GG) {
    float cnt = fmaxf((float)gcnt[t] * (float)DD, 1.0f);
    float mu  = gsum[t] / cnt;
    float var = gsq[t] / cnt - mu * mu;
    var = fmaxf(var, 0.0f);
    gmu[t]   = mu;
    grstd[t] = rsqrtf(var + 1e-5f);
  }
}

// ---------------- graph-LN normalize (elementwise) ----------------
__global__ __launch_bounds__(256) void k_norm(float* __restrict__ x, const int* __restrict__ batch,
                                              const float* __restrict__ gmu, const float* __restrict__ grstd,
                                              const float* __restrict__ lnw, const float* __restrict__ lnb) {
  for (int i = blockIdx.x * 256 + threadIdx.x; i < NN * DD; i += gridDim.x * 256) {
    int n = i >> 9, d = i & 511;
    int g = batch[n];
    x[i] = (x[i] - gmu[g]) * grstd[g] * lnw[d] + lnb[d];
  }
}

// ---------------- pooling: mean + max per graph (batch_vec sorted) ----------------
__device__ __forceinline__ int lowb(const int* a, int n, int key) {
  int lo = 0, hi = n;
  while (lo < hi) { int mid = (lo + hi) >> 1; if (a[mid] < key) lo = mid + 1; else hi = mid; }
  return lo;
}

__global__ __launch_bounds__(256) void k_pool(const float* __restrict__ x, const int* __restrict__ batch,
                                              float* __restrict__ pool) {
  int g = blockIdx.x, tid = threadIdx.x;
  __shared__ int sb, se;
  if (tid == 0) { sb = lowb(batch, NN, g); se = lowb(batch, NN, g + 1); }
  __syncthreads();
  int b = sb, e = se;
  float s0 = 0.f, s1 = 0.f, m0 = -INFINITY, m1 = -INFINITY;
  for (int n = b; n < e; ++n) {
    float v0 = x[(size_t)n * DD + tid];
    float v1 = x[(size_t)n * DD + tid + 256];
    s0 += v0; s1 += v1;
    m0 = fmaxf(m0, v0); m1 = fmaxf(m1, v1);
  }
  int cnt = e - b;
  float inv = 1.0f / (float)(cnt > 0 ? cnt : 1);
  pool[(size_t)g * 1024 + tid]             = s0 * inv;
  pool[(size_t)g * 1024 + tid + 256]       = s1 * inv;
  pool[(size_t)g * 1024 + 512 + tid]       = (cnt > 0) ? m0 : 0.f;
  pool[(size_t)g * 1024 + 512 + tid + 256] = (cnt > 0) ? m1 : 0.f;
}

// ---------------- final row L2 normalize ----------------
__global__ __launch_bounds__(256) void k_l2(float* __restrict__ h) {
  int g = blockIdx.x, t = threadIdx.x;
  float v = h[(size_t)g * OUTD + t];
  float q = v * v;
#pragma unroll
  for (int o = 32; o; o >>= 1) q += __shfl_xor(q, o);
  __shared__ float w[4];
  int wv = t >> 6, ln = t & 63;
  if (ln == 0) w[wv] = q;
  __syncthreads();
  float tot = w[0] + w[1] + w[2] + w[3];
  float nrm = fmaxf(sqrtf(tot), 1e-12f);
  h[(size_t)g * OUTD + t] = v / nrm;
}

// ---------------- launcher ----------------
extern "C" void kernel_launch(void* const* d_in, const int* in_sizes, int n_in,
                              void* d_out, int out_size, void* d_ws, size_t ws_size,
                              hipStream_t stream) {
  const int*   node_ids = (const int*)d_in[0];
  const int*   ei       = (const int*)d_in[1];
  const int*   batch    = (const int*)d_in[2];
  const float* emb      = (const float*)d_in[3];
  const float* W[4]  = {(const float*)d_in[4],  (const float*)d_in[10], (const float*)d_in[16], (const float*)d_in[22]};
  const float* AS[4] = {(const float*)d_in[5],  (const float*)d_in[11], (const float*)d_in[17], (const float*)d_in[23]};
  const float* AD[4] = {(const float*)d_in[6],  (const float*)d_in[12], (const float*)d_in[18], (const float*)d_in[24]};
  const float* BV[4] = {(const float*)d_in[7],  (const float*)d_in[13], (const float*)d_in[19], (const float*)d_in[25]};
  const float* LW[4] = {(const float*)d_in[8],  (const float*)d_in[14], (const float*)d_in[20], (const float*)d_in[26]};
  const float* LB[4] = {(const float*)d_in[9],  (const float*)d_in[15], (const float*)d_in[21], (const float*)d_in[27]};
  const float* res_w0 = (const float*)d_in[28];
  const float* p1w    = (const float*)d_in[29];
  const float* p1b    = (const float*)d_in[30];
  const float* p2w    = (const float*)d_in[31];
  const float* p2b    = (const float*)d_in[32];
  float* out = (float*)d_out;

  char* ws = (char*)d_ws;
  size_t pos = 0;
  auto alloc = [&](size_t bytes) -> char* {
    char* p = ws + pos;
    pos = (pos + bytes + 255) & ~size_t(255);
    return p;
  };
  float* x0    = (float*)alloc((size_t)NN * DEE * 4);
  float* xb    = (float*)alloc((size_t)NN * DD * 4);
  float* xp    = (float*)alloc((size_t)NN * DD * 4);
  float* ssrc  = (float*)alloc((size_t)NN * 4 * 4);
  float* sdst  = (float*)alloc((size_t)NN * 4 * 4);
  int*   coff  = (int*)alloc((size_t)(NN + 1) * 4);
  int*   ccur  = (int*)alloc((size_t)NN * 4);
  int*   csrc  = (int*)alloc((size_t)ET * 4);
  int*   gcnt  = (int*)alloc((size_t)GG * 4);
  float* gsum  = (float*)alloc((size_t)GG * 4 * 2);
  float* gsq   = gsum + GG;
  float* gmu   = (float*)alloc((size_t)GG * 4 * 2);
  float* grstd = gmu + GG;
  float* pool  = (float*)alloc((size_t)GG * 1024 * 4);
  float* h1    = (float*)alloc((size_t)GG * 1024 * 4);
  (void)ws_size; (void)in_sizes; (void)n_in; (void)out_size;

  // ---- CSR + graph histogram ----
  hipMemsetAsync(ccur, 0, (size_t)NN * 4, stream);
  hipMemsetAsync(gcnt, 0, (size_t)GG * 4, stream);
  k_embed<<<2048, 256, 0, stream>>>(node_ids, emb, x0);
  k_gcnt<<<256, 256, 0, stream>>>(batch, gcnt);
  k_count<<<1024, 256, 0, stream>>>(ei, ccur);
  k_scan<<<1, 1024, 0, stream>>>(ccur, coff);
  hipMemsetAsync(ccur, 0, (size_t)NN * 4, stream);
  k_scatter<<<1024, 256, 0, stream>>>(ei, coff, ccur, csrc);

  // ---- 4 GAT layers ----
  for (int L = 0; L < 4; ++L) {
    if (L == 0) {
      k_gemm<<<dim3(313, 8), 256, 0, stream>>>(x0, W[0],   xp, nullptr, NN, DD, DEE, 0);
      k_gemm<<<dim3(313, 8), 256, 0, stream>>>(x0, res_w0, xb, nullptr, NN, DD, DEE, 0);
    } else {
      k_gemm<<<dim3(313, 8), 256, 0, stream>>>(xb, W[L], xp, nullptr, NN, DD, DD, 0);
    }
    k_sdots<<<NN, 256, 0, stream>>>(xp, AS[L], AD[L], ssrc, sdst);
    hipMemsetAsync(gsum, 0, (size_t)GG * 8, stream);
    k_agg<<<NN, 256, 0, stream>>>(xp, ssrc, sdst, coff, csrc, batch, BV[L], xb, gsum, gsq);
    k_stats<<<1, GG, 0, stream>>>(gcnt, gsum, gsq, gmu, grstd);
    k_norm<<<2048, 256, 0, stream>>>(xb, batch, gmu, grstd, LW[L], LB[L]);
  }

  // ---- pool + MLP head + normalize ----
  k_pool<<<GG, 256, 0, stream>>>(xb, batch, pool);
  k_gemm<<<dim3(2, 16), 256, 0, stream>>>(pool, p1w, h1, p1b, GG, 1024, 1024, 2);
  k_gemm<<<dim3(2, 4), 256, 0, stream>>>(h1, p2w, out, p2b, GG, OUTD, 1024, 1);
  k_l2<<<GG, 256, 0, stream>>>(out);
}

// Round 2
// 1487.397 us; speedup vs baseline: 1.0914x; 1.0914x over previous
//
#include <hip/hip_runtime.h>
#include <math.h>

constexpr int NN   = 20000;
constexpr int EE   = 320000;
constexpr int ET   = EE + NN;   // 340000 with self loops
constexpr int GG   = 128;
constexpr int DEE  = 64;
constexpr int DD   = 512;
constexpr int OUTD = 256;

// ---------------- embedding gather ----------------
__global__ __launch_bounds__(256) void k_embed(const int* __restrict__ ids,
                                               const float* __restrict__ emb,
                                               float* __restrict__ x0) {
  for (int i = blockIdx.x * 256 + threadIdx.x; i < NN * DEE; i += gridDim.x * 256) {
    int n = i >> 6, d = i & 63;
    x0[i] = emb[ids[n] * DEE + d];
  }
}

// ---------------- graph node-count histogram ----------------
__global__ __launch_bounds__(256) void k_gcnt(const int* __restrict__ batch, int* __restrict__ gcnt) {
  for (int n = blockIdx.x * 256 + threadIdx.x; n < NN; n += gridDim.x * 256)
    atomicAdd(&gcnt[batch[n]], 1);
}

// ---------------- CSR build ----------------
__global__ __launch_bounds__(256) void k_count(const int* __restrict__ ei, int* __restrict__ cnt) {
  for (int k = blockIdx.x * 256 + threadIdx.x; k < ET; k += gridDim.x * 256) {
    int d = (k < EE) ? ei[EE + k] : (k - EE);
    atomicAdd(&cnt[d], 1);
  }
}

__global__ __launch_bounds__(1024) void k_scan(const int* __restrict__ cnt, int* __restrict__ off) {
  __shared__ int part[1024];
  int tid = threadIdx.x;
  constexpr int CH = (NN + 1023) / 1024;  // 20
  int base = tid * CH;
  int s = 0;
  for (int i = 0; i < CH; ++i) { int idx = base + i; if (idx < NN) s += cnt[idx]; }
  part[tid] = s;
  __syncthreads();
  for (int o = 1; o < 1024; o <<= 1) {
    int add = (tid >= o) ? part[tid - o] : 0;
    int v = part[tid];
    __syncthreads();
    part[tid] = v + add;
    __syncthreads();
  }
  int run = (tid == 0) ? 0 : part[tid - 1];
  for (int i = 0; i < CH; ++i) {
    int idx = base + i;
    if (idx < NN) { off[idx] = run; run += cnt[idx]; }
  }
  if (tid == 1023) off[NN] = ET;
}

__global__ __launch_bounds__(256) void k_scatter(const int* __restrict__ ei, const int* __restrict__ off,
                                                 int* __restrict__ cur, int* __restrict__ csrc) {
  for (int k = blockIdx.x * 256 + threadIdx.x; k < ET; k += gridDim.x * 256) {
    int s = (k < EE) ? ei[k]      : (k - EE);
    int d = (k < EE) ? ei[EE + k] : (k - EE);
    int p = atomicAdd(&cur[d], 1);
    csrc[off[d] + p] = s;
  }
}

// ---------------- fp32 tiled GEMM 128x128, N fixed = 512 ----------------
__global__ __launch_bounds__(256) void k_gemm128(const float* __restrict__ A, const float* __restrict__ B,
                                                 float* __restrict__ Cout, int M, int K) {
  __shared__ float As[16][132];
  __shared__ float Bs[16][132];
  int tid = threadIdx.x;
  int n0 = blockIdx.x * 128, m0 = blockIdx.y * 128;
  int tx = tid & 15, ty = tid >> 4;
  int lar = tid >> 1, lak = (tid & 1) * 8;
  int lbr = tid >> 4, lbc = (tid & 15) * 8;
  float acc[8][8] = {};
  for (int k0 = 0; k0 < K; k0 += 16) {
    float4 a0, a1;
    int ar = m0 + lar;
    if (ar < M) {
      a0 = *(const float4*)(A + (size_t)ar * K + k0 + lak);
      a1 = *(const float4*)(A + (size_t)ar * K + k0 + lak + 4);
    } else { a0 = make_float4(0.f,0.f,0.f,0.f); a1 = a0; }
    As[lak+0][lar]=a0.x; As[lak+1][lar]=a0.y; As[lak+2][lar]=a0.z; As[lak+3][lar]=a0.w;
    As[lak+4][lar]=a1.x; As[lak+5][lar]=a1.y; As[lak+6][lar]=a1.z; As[lak+7][lar]=a1.w;
    const float* brow = B + (size_t)(k0 + lbr) * DD + n0 + lbc;
    *(float4*)&Bs[lbr][lbc]     = *(const float4*)brow;
    *(float4*)&Bs[lbr][lbc + 4] = *(const float4*)(brow + 4);
    __syncthreads();
#pragma unroll
    for (int kk = 0; kk < 16; ++kk) {
      float4 a0v = *(const float4*)&As[kk][ty * 4];
      float4 a1v = *(const float4*)&As[kk][64 + ty * 4];
      float4 b0v = *(const float4*)&Bs[kk][tx * 4];
      float4 b1v = *(const float4*)&Bs[kk][64 + tx * 4];
      float av[8] = {a0v.x,a0v.y,a0v.z,a0v.w,a1v.x,a1v.y,a1v.z,a1v.w};
      float bv[8] = {b0v.x,b0v.y,b0v.z,b0v.w,b1v.x,b1v.y,b1v.z,b1v.w};
#pragma unroll
      for (int i = 0; i < 8; ++i)
#pragma unroll
        for (int j = 0; j < 8; ++j)
          acc[i][j] = fmaf(av[i], bv[j], acc[i][j]);
    }
    __syncthreads();
  }
#pragma unroll
  for (int i = 0; i < 8; ++i) {
    int row = m0 + (i < 4 ? ty * 4 + i : 64 + ty * 4 + i - 4);
    if (row >= M) continue;
    float4 c0 = make_float4(acc[i][0], acc[i][1], acc[i][2], acc[i][3]);
    float4 c1 = make_float4(acc[i][4], acc[i][5], acc[i][6], acc[i][7]);
    *(float4*)(Cout + (size_t)row * DD + n0 + tx * 4)      = c0;
    *(float4*)(Cout + (size_t)row * DD + n0 + 64 + tx * 4) = c1;
  }
}

// ---------------- fp32 tiled GEMM 64x64 (small head GEMMs) ----------------
// mode: 0 = plain, 1 = +bias, 2 = +bias then exact GELU
__global__ __launch_bounds__(256) void k_gemm(const float* __restrict__ A, const float* __restrict__ B,
                                              float* __restrict__ Cout, const float* __restrict__ bias,
                                              int M, int Nc, int K, int mode) {
  __shared__ float As[16][68];
  __shared__ float Bs[16][68];
  int tid = threadIdx.x;
  int m0 = blockIdx.x * 64, n0 = blockIdx.y * 64;
  int tx = tid & 15, ty = tid >> 4;
  int lam = tid >> 2, lak = (tid & 3) * 4;
  int lbk = tid >> 4, lbn = (tid & 15) * 4;
  float acc[4][4] = {};
  int ar = m0 + lam;
  for (int k0 = 0; k0 < K; k0 += 16) {
    float4 av;
    if (ar < M) av = *(const float4*)(A + (size_t)ar * K + k0 + lak);
    else        av = make_float4(0.f, 0.f, 0.f, 0.f);
    As[lak + 0][lam] = av.x; As[lak + 1][lam] = av.y;
    As[lak + 2][lam] = av.z; As[lak + 3][lam] = av.w;
    *(float4*)&Bs[lbk][lbn] = *(const float4*)(B + (size_t)(k0 + lbk) * Nc + n0 + lbn);
    __syncthreads();
#pragma unroll
    for (int kk = 0; kk < 16; ++kk) {
      const float4 a4 = *(const float4*)&As[kk][ty << 2];
      const float4 b4 = *(const float4*)&Bs[kk][tx << 2];
      const float a[4] = {a4.x, a4.y, a4.z, a4.w};
      const float b[4] = {b4.x, b4.y, b4.z, b4.w};
#pragma unroll
      for (int i = 0; i < 4; ++i)
#pragma unroll
        for (int j = 0; j < 4; ++j)
          acc[i][j] = fmaf(a[i], b[j], acc[i][j]);
    }
    __syncthreads();
  }
#pragma unroll
  for (int i = 0; i < 4; ++i) {
    int row = m0 + ty * 4 + i;
    if (row >= M) continue;
#pragma unroll
    for (int j = 0; j < 4; ++j) {
      int col = n0 + tx * 4 + j;
      float v = acc[i][j];
      if (mode >= 1) v += bias[col];
      if (mode == 2) v = 0.5f * v * (1.0f + erff(v * 0.70710678118654752f));
      Cout[(size_t)row * Nc + col] = v;
    }
  }
}

// ---------------- attention score dots: s_src/s_dst [N,4] ----------------
__global__ __launch_bounds__(256) void k_sdots(const float* __restrict__ xp,
                                               const float* __restrict__ asw,
                                               const float* __restrict__ adw,
                                               float* __restrict__ ssrc, float* __restrict__ sdst) {
  int n = blockIdx.x;
  int t = threadIdx.x;
  int h = t >> 6;
  int l = t & 63;
  const float* row = xp + (size_t)n * DD + h * 128;
  float a = 0.f, b = 0.f;
  for (int c = l; c < 128; c += 64) {
    float v = row[c];
    a += v * asw[h * 128 + c];
    b += v * adw[h * 128 + c];
  }
#pragma unroll
  for (int o = 32; o; o >>= 1) { a += __shfl_down(a, o); b += __shfl_down(b, o); }
  if (l == 0) { ssrc[n * 4 + h] = a; sdst[n * 4 + h] = b; }
}

// ---------------- wave-per-node edge-softmax aggregation ----------------
__global__ __launch_bounds__(256) void k_agg(const float* __restrict__ xp,
                                             const float* __restrict__ ssrc,
                                             const float* __restrict__ sdst,
                                             const int* __restrict__ off,
                                             const int* __restrict__ csr,
                                             const int* __restrict__ batch,
                                             const float* __restrict__ bias,
                                             float* __restrict__ xio,   // in: residual, out: pre-LN
                                             float* __restrict__ gsum, float* __restrict__ gsq) {
  int wv = threadIdx.x >> 6, ln = threadIdx.x & 63;
  int n = blockIdx.x * 4 + wv;         // NN % 4 == 0
  int beg = off[n], end = off[n + 1];
  int h = ln >> 4;

  float4 sd4 = *(const float4*)(sdst + (size_t)n * 4);
  float sdv[4] = {sd4.x, sd4.y, sd4.z, sd4.w};

  // ---- stage 1: per-head softmax max & denom (lane-strided, then butterfly) ----
  float m[4] = {-INFINITY, -INFINITY, -INFINITY, -INFINITY};
  float s[4] = {0.f, 0.f, 0.f, 0.f};
  for (int k = beg + ln; k < end; k += 64) {
    int sk = csr[k];
    float4 sv = *(const float4*)(ssrc + (size_t)sk * 4);
    float ev[4] = {sv.x, sv.y, sv.z, sv.w};
#pragma unroll
    for (int hh = 0; hh < 4; ++hh) {
      float e = ev[hh] + sdv[hh];
      e = (e > 0.f) ? e : 0.2f * e;
      float nm = fmaxf(m[hh], e);
      s[hh] = s[hh] * expf(m[hh] - nm) + expf(e - nm);
      m[hh] = nm;
    }
  }
#pragma unroll
  for (int o = 32; o; o >>= 1) {
#pragma unroll
    for (int hh = 0; hh < 4; ++hh) {
      float om = __shfl_xor(m[hh], o);
      float os = __shfl_xor(s[hh], o);
      float M = fmaxf(m[hh], om);
      if (M > -1e37f) {
        s[hh] = s[hh] * expf(m[hh] - M) + os * expf(om - M);
        m[hh] = M;
      }
    }
  }
  float mh  = m[h];
  float inv = 1.0f / s[h];
  float sdh = sdv[h];

  // ---- stage 2: weighted gather-accumulate, 2-edge unroll for ILP ----
  const int d = ln * 8;
  float accA[8] = {}, accB[8] = {};
  int k = beg;
  for (; k + 1 < end; k += 2) {
    int skA = csr[k], skB = csr[k + 1];
    float eA = ssrc[(size_t)skA * 4 + h] + sdh;
    float eB = ssrc[(size_t)skB * 4 + h] + sdh;
    eA = (eA > 0.f) ? eA : 0.2f * eA;
    eB = (eB > 0.f) ? eB : 0.2f * eB;
    float wA = expf(eA - mh);
    float wB = expf(eB - mh);
    const float4 xa0 = *(const float4*)(xp + (size_t)skA * DD + d);
    const float4 xa1 = *(const float4*)(xp + (size_t)skA * DD + d + 4);
    const float4 xb0 = *(const float4*)(xp + (size_t)skB * DD + d);
    const float4 xb1 = *(const float4*)(xp + (size_t)skB * DD + d + 4);
    accA[0] += wA * xa0.x; accA[1] += wA * xa0.y; accA[2] += wA * xa0.z; accA[3] += wA * xa0.w;
    accA[4] += wA * xa1.x; accA[5] += wA * xa1.y; accA[6] += wA * xa1.z; accA[7] += wA * xa1.w;
    accB[0] += wB * xb0.x; accB[1] += wB * xb0.y; accB[2] += wB * xb0.z; accB[3] += wB * xb0.w;
    accB[4] += wB * xb1.x; accB[5] += wB * xb1.y; accB[6] += wB * xb1.z; accB[7] += wB * xb1.w;
  }
  if (k < end) {
    int sk = csr[k];
    float e = ssrc[(size_t)sk * 4 + h] + sdh;
    e = (e > 0.f) ? e : 0.2f * e;
    float w = expf(e - mh);
    const float4 x0 = *(const float4*)(xp + (size_t)sk * DD + d);
    const float4 x1 = *(const float4*)(xp + (size_t)sk * DD + d + 4);
    accA[0] += w * x0.x; accA[1] += w * x0.y; accA[2] += w * x0.z; accA[3] += w * x0.w;
    accA[4] += w * x1.x; accA[5] += w * x1.y; accA[6] += w * x1.z; accA[7] += w * x1.w;
  }

  // ---- epilogue: alpha-normalize, +bias, +residual, write, LN partials ----
  float4 b0 = *(const float4*)(bias + d);
  float4 b1 = *(const float4*)(bias + d + 4);
  float4 r0 = *(const float4*)(xio + (size_t)n * DD + d);
  float4 r1 = *(const float4*)(xio + (size_t)n * DD + d + 4);
  float bv[8] = {b0.x,b0.y,b0.z,b0.w,b1.x,b1.y,b1.z,b1.w};
  float rv[8] = {r0.x,r0.y,r0.z,r0.w,r1.x,r1.y,r1.z,r1.w};
  float o[8];
  float ps = 0.f, pq = 0.f;
#pragma unroll
  for (int i = 0; i < 8; ++i) {
    o[i] = (accA[i] + accB[i]) * inv + bv[i] + rv[i];
    ps += o[i];
    pq += o[i] * o[i];
  }
  *(float4*)(xio + (size_t)n * DD + d)     = make_float4(o[0], o[1], o[2], o[3]);
  *(float4*)(xio + (size_t)n * DD + d + 4) = make_float4(o[4], o[5], o[6], o[7]);
#pragma unroll
  for (int oo = 32; oo; oo >>= 1) { ps += __shfl_xor(ps, oo); pq += __shfl_xor(pq, oo); }
  if (ln == 0) {
    int g = batch[n];
    atomicAdd(&gsum[g], ps);
    atomicAdd(&gsq[g], pq);
  }
}

// ---------------- per-graph LN stats ----------------
__global__ void k_stats(const int* __restrict__ gcnt, const float* __restrict__ gsum,
                        const float* __restrict__ gsq, float* __restrict__ gmu, float* __restrict__ grstd) {
  int t = threadIdx.x;
  if (t < GG) {
    float cnt = fmaxf((float)gcnt[t] * (float)DD, 1.0f);
    float mu  = gsum[t] / cnt;
    float var = gsq[t] / cnt - mu * mu;
    var = fmaxf(var, 0.0f);
    gmu[t]   = mu;
    grstd[t] = rsqrtf(var + 1e-5f);
  }
}

// ---------------- graph-LN normalize (elementwise) ----------------
__global__ __launch_bounds__(256) void k_norm(float* __restrict__ x, const int* __restrict__ batch,
                                              const float* __restrict__ gmu, const float* __restrict__ grstd,
                                              const float* __restrict__ lnw, const float* __restrict__ lnb) {
  for (int i = blockIdx.x * 256 + threadIdx.x; i < NN * DD; i += gridDim.x * 256) {
    int n = i >> 9, d = i & 511;
    int g = batch[n];
    x[i] = (x[i] - gmu[g]) * grstd[g] * lnw[d] + lnb[d];
  }
}

// ---------------- pooling: mean + max per graph (batch_vec sorted) ----------------
__device__ __forceinline__ int lowb(const int* a, int n, int key) {
  int lo = 0, hi = n;
  while (lo < hi) { int mid = (lo + hi) >> 1; if (a[mid] < key) lo = mid + 1; else hi = mid; }
  return lo;
}

__global__ __launch_bounds__(256) void k_pool(const float* __restrict__ x, const int* __restrict__ batch,
                                              float* __restrict__ pool) {
  int g = blockIdx.x, tid = threadIdx.x;
  __shared__ int sb, se;
  if (tid == 0) { sb = lowb(batch, NN, g); se = lowb(batch, NN, g + 1); }
  __syncthreads();
  int b = sb, e = se;
  float s0 = 0.f, s1 = 0.f, m0 = -INFINITY, m1 = -INFINITY;
  for (int n = b; n < e; ++n) {
    float v0 = x[(size_t)n * DD + tid];
    float v1 = x[(size_t)n * DD + tid + 256];
    s0 += v0; s1 += v1;
    m0 = fmaxf(m0, v0); m1 = fmaxf(m1, v1);
  }
  int cnt = e - b;
  float inv = 1.0f / (float)(cnt > 0 ? cnt : 1);
  pool[(size_t)g * 1024 + tid]             = s0 * inv;
  pool[(size_t)g * 1024 + tid + 256]       = s1 * inv;
  pool[(size_t)g * 1024 + 512 + tid]       = (cnt > 0) ? m0 : 0.f;
  pool[(size_t)g * 1024 + 512 + tid + 256] = (cnt > 0) ? m1 : 0.f;
}

// ---------------- final row L2 normalize ----------------
__global__ __launch_bounds__(256) void k_l2(float* __restrict__ h) {
  int g = blockIdx.x, t = threadIdx.x;
  float v = h[(size_t)g * OUTD + t];
  float q = v * v;
#pragma unroll
  for (int o = 32; o; o >>= 1) q += __shfl_xor(q, o);
  __shared__ float w[4];
  int wv = t >> 6, ln = t & 63;
  if (ln == 0) w[wv] = q;
  __syncthreads();
  float tot = w[0] + w[1] + w[2] + w[3];
  float nrm = fmaxf(sqrtf(tot), 1e-12f);
  h[(size_t)g * OUTD + t] = v / nrm;
}

// ---------------- launcher ----------------
extern "C" void kernel_launch(void* const* d_in, const int* in_sizes, int n_in,
                              void* d_out, int out_size, void* d_ws, size_t ws_size,
                              hipStream_t stream) {
  const int*   node_ids = (const int*)d_in[0];
  const int*   ei       = (const int*)d_in[1];
  const int*   batch    = (const int*)d_in[2];
  const float* emb      = (const float*)d_in[3];
  const float* W[4]  = {(const float*)d_in[4],  (const float*)d_in[10], (const float*)d_in[16], (const float*)d_in[22]};
  const float* AS[4] = {(const float*)d_in[5],  (const float*)d_in[11], (const float*)d_in[17], (const float*)d_in[23]};
  const float* AD[4] = {(const float*)d_in[6],  (const float*)d_in[12], (const float*)d_in[18], (const float*)d_in[24]};
  const float* BV[4] = {(const float*)d_in[7],  (const float*)d_in[13], (const float*)d_in[19], (const float*)d_in[25]};
  const float* LW[4] = {(const float*)d_in[8],  (const float*)d_in[14], (const float*)d_in[20], (const float*)d_in[26]};
  const float* LB[4] = {(const float*)d_in[9],  (const float*)d_in[15], (const float*)d_in[21], (const float*)d_in[27]};
  const float* res_w0 = (const float*)d_in[28];
  const float* p1w    = (const float*)d_in[29];
  const float* p1b    = (const float*)d_in[30];
  const float* p2w    = (const float*)d_in[31];
  const float* p2b    = (const float*)d_in[32];
  float* out = (float*)d_out;

  char* ws = (char*)d_ws;
  size_t pos = 0;
  auto alloc = [&](size_t bytes) -> char* {
    char* p = ws + pos;
    pos = (pos + bytes + 255) & ~size_t(255);
    return p;
  };
  float* x0    = (float*)alloc((size_t)NN * DEE * 4);
  float* xb    = (float*)alloc((size_t)NN * DD * 4);
  float* xp    = (float*)alloc((size_t)NN * DD * 4);
  float* ssrc  = (float*)alloc((size_t)NN * 4 * 4);
  float* sdst  = (float*)alloc((size_t)NN * 4 * 4);
  int*   coff  = (int*)alloc((size_t)(NN + 1) * 4);
  int*   ccur  = (int*)alloc((size_t)NN * 4);
  int*   csrc  = (int*)alloc((size_t)ET * 4);
  int*   gcnt  = (int*)alloc((size_t)GG * 4);
  float* gsum  = (float*)alloc((size_t)GG * 4 * 2);
  float* gsq   = gsum + GG;
  float* gmu   = (float*)alloc((size_t)GG * 4 * 2);
  float* grstd = gmu + GG;
  float* pool  = (float*)alloc((size_t)GG * 1024 * 4);
  float* h1    = (float*)alloc((size_t)GG * 1024 * 4);
  (void)ws_size; (void)in_sizes; (void)n_in; (void)out_size;

  // ---- CSR + graph histogram ----
  hipMemsetAsync(ccur, 0, (size_t)NN * 4, stream);
  hipMemsetAsync(gcnt, 0, (size_t)GG * 4, stream);
  k_embed<<<2048, 256, 0, stream>>>(node_ids, emb, x0);
  k_gcnt<<<256, 256, 0, stream>>>(batch, gcnt);
  k_count<<<1024, 256, 0, stream>>>(ei, ccur);
  k_scan<<<1, 1024, 0, stream>>>(ccur, coff);
  hipMemsetAsync(ccur, 0, (size_t)NN * 4, stream);
  k_scatter<<<1024, 256, 0, stream>>>(ei, coff, ccur, csrc);

  // ---- 4 GAT layers ----
  for (int L = 0; L < 4; ++L) {
    if (L == 0) {
      k_gemm128<<<dim3(4, 157), 256, 0, stream>>>(x0, W[0],   xp, NN, DEE);
      k_gemm128<<<dim3(4, 157), 256, 0, stream>>>(x0, res_w0, xb, NN, DEE);
    } else {
      k_gemm128<<<dim3(4, 157), 256, 0, stream>>>(xb, W[L], xp, NN, DD);
    }
    k_sdots<<<NN, 256, 0, stream>>>(xp, AS[L], AD[L], ssrc, sdst);
    hipMemsetAsync(gsum, 0, (size_t)GG * 8, stream);
    k_agg<<<NN / 4, 256, 0, stream>>>(xp, ssrc, sdst, coff, csrc, batch, BV[L], xb, gsum, gsq);
    k_stats<<<1, GG, 0, stream>>>(gcnt, gsum, gsq, gmu, grstd);
    k_norm<<<2048, 256, 0, stream>>>(xb, batch, gmu, grstd, LW[L], LB[L]);
  }

  // ---- pool + MLP head + normalize ----
  k_pool<<<GG, 256, 0, stream>>>(xb, batch, pool);
  k_gemm<<<dim3(2, 16), 256, 0, stream>>>(pool, p1w, h1, p1b, GG, 1024, 1024, 2);
  k_gemm<<<dim3(2, 4), 256, 0, stream>>>(h1, p2w, out, p2b, GG, OUTD, 1024, 1);
  k_l2<<<GG, 256, 0, stream>>>(out);
}

// Round 3
// 1318.274 us; speedup vs baseline: 1.2315x; 1.1283x over previous
//
#include <hip/hip_runtime.h>
#include <hip/hip_fp16.h>
#include <math.h>

constexpr int NN   = 20000;
constexpr int EE   = 320000;
constexpr int ET   = EE + NN;   // 340000 with self loops
constexpr int GG   = 128;
constexpr int DEE  = 64;
constexpr int DD   = 512;
constexpr int OUTD = 256;

using bf16x8 = __attribute__((ext_vector_type(8))) short;
using f32x4  = __attribute__((ext_vector_type(4))) float;

__device__ __forceinline__ unsigned short f2bf(float f) {
  union { float f; unsigned u; } v; v.f = f;
  unsigned r = v.u + 0x7FFF + ((v.u >> 16) & 1);   // RNE
  return (unsigned short)(r >> 16);
}
__device__ __forceinline__ float bf2f(unsigned short h) {
  union { unsigned u; float f; } v; v.u = ((unsigned)h) << 16; return v.f;
}

// ---------------- embedding gather + bf16 hi/lo split ----------------
__global__ __launch_bounds__(256) void k_embsplit(const int* __restrict__ ids,
                                                  const float* __restrict__ emb,
                                                  ushort* __restrict__ xh, ushort* __restrict__ xl) {
  for (int i = blockIdx.x * 256 + threadIdx.x; i < NN * 16; i += gridDim.x * 256) {
    int n = i >> 4, q = i & 15;
    float4 v = *(const float4*)(emb + (size_t)ids[n] * DEE + q * 4);
    ushort4 hi, lo;
    hi.x = f2bf(v.x); lo.x = f2bf(v.x - bf2f(hi.x));
    hi.y = f2bf(v.y); lo.y = f2bf(v.y - bf2f(hi.y));
    hi.z = f2bf(v.z); lo.z = f2bf(v.z - bf2f(hi.z));
    hi.w = f2bf(v.w); lo.w = f2bf(v.w - bf2f(hi.w));
    *(ushort4*)(xh + (size_t)n * DEE + q * 4) = hi;
    *(ushort4*)(xl + (size_t)n * DEE + q * 4) = lo;
  }
}

// ---------------- weight transpose + bf16 hi/lo split: Wt[n][k] = W[k][n] ----------------
__global__ __launch_bounds__(256) void k_wsplitT(const float* __restrict__ W,
                                                 ushort* __restrict__ Th, ushort* __restrict__ Tl,
                                                 int K, int N) {
  __shared__ float t[32][33];
  int n0 = blockIdx.x * 32, k0 = blockIdx.y * 32;
  int c = threadIdx.x & 31, r4 = threadIdx.x >> 5;   // 32 cols x 8 rows per pass
  for (int rr = 0; rr < 32; rr += 8)
    t[rr + r4][c] = W[(size_t)(k0 + rr + r4) * N + n0 + c];
  __syncthreads();
  for (int rr = 0; rr < 32; rr += 8) {
    int n = n0 + rr + r4, k = k0 + c;
    float v = t[c][rr + r4];
    unsigned short hi = f2bf(v);
    Th[(size_t)n * K + k] = hi;
    Tl[(size_t)n * K + k] = f2bf(v - bf2f(hi));
  }
}

// ---------------- graph node-count histogram ----------------
__global__ __launch_bounds__(256) void k_gcnt(const int* __restrict__ batch, int* __restrict__ gcnt) {
  for (int n = blockIdx.x * 256 + threadIdx.x; n < NN; n += gridDim.x * 256)
    atomicAdd(&gcnt[batch[n]], 1);
}

// ---------------- CSR build ----------------
__global__ __launch_bounds__(256) void k_count(const int* __restrict__ ei, int* __restrict__ cnt) {
  for (int k = blockIdx.x * 256 + threadIdx.x; k < ET; k += gridDim.x * 256) {
    int d = (k < EE) ? ei[EE + k] : (k - EE);
    atomicAdd(&cnt[d], 1);
  }
}

__global__ __launch_bounds__(1024) void k_scan(const int* __restrict__ cnt, int* __restrict__ off) {
  __shared__ int part[1024];
  int tid = threadIdx.x;
  constexpr int CH = (NN + 1023) / 1024;  // 20
  int base = tid * CH;
  int s = 0;
  for (int i = 0; i < CH; ++i) { int idx = base + i; if (idx < NN) s += cnt[idx]; }
  part[tid] = s;
  __syncthreads();
  for (int o = 1; o < 1024; o <<= 1) {
    int add = (tid >= o) ? part[tid - o] : 0;
    int v = part[tid];
    __syncthreads();
    part[tid] = v + add;
    __syncthreads();
  }
  int run = (tid == 0) ? 0 : part[tid - 1];
  for (int i = 0; i < CH; ++i) {
    int idx = base + i;
    if (idx < NN) { off[idx] = run; run += cnt[idx]; }
  }
  if (tid == 1023) off[NN] = ET;
}

__global__ __launch_bounds__(256) void k_scatter(const int* __restrict__ ei, const int* __restrict__ off,
                                                 int* __restrict__ cur, int* __restrict__ csrc) {
  for (int k = blockIdx.x * 256 + threadIdx.x; k < ET; k += gridDim.x * 256) {
    int s = (k < EE) ? ei[k]      : (k - EE);
    int d = (k < EE) ? ei[EE + k] : (k - EE);
    int p = atomicAdd(&cur[d], 1);
    csrc[off[d] + p] = s;
  }
}

// ---------------- bf16x3-split MFMA GEMM: C[M,512] = A[M,K] @ B[K,512] ----------------
// A given as hi/lo bf16 row-major [M][K]; B given as hi/lo bf16 TRANSPOSED [512][K].
// OUT16=1: write __half; OUT16=0: write float.
template<int OUT16>
__global__ __launch_bounds__(256) void k_mfma(const ushort* __restrict__ Ah, const ushort* __restrict__ Al,
                                              const ushort* __restrict__ Bh, const ushort* __restrict__ Bl,
                                              void* __restrict__ Cout, int M, int K) {
  int tid = threadIdx.x, l = tid & 63, w = tid >> 6;
  int wr = w >> 1, wc = w & 1;
  int m0 = blockIdx.y * 128 + wr * 64, n0 = blockIdx.x * 128 + wc * 64;
  int l15 = l & 15, l16 = l >> 4;
  int aoff[4], boff[4];
#pragma unroll
  for (int t = 0; t < 4; ++t) {
    int r = m0 + t * 16 + l15; r = min(r, M - 1);
    aoff[t] = r * K + l16 * 8;
    boff[t] = (n0 + t * 16 + l15) * K + l16 * 8;
  }
  f32x4 acc[4][4] = {};
  for (int k0 = 0; k0 < K; k0 += 32) {
    bf16x8 ah[4], al[4], bh[4], bl[4];
#pragma unroll
    for (int t = 0; t < 4; ++t) {
      ah[t] = *(const bf16x8*)(Ah + aoff[t]);
      al[t] = *(const bf16x8*)(Al + aoff[t]);
      bh[t] = *(const bf16x8*)(Bh + boff[t]);
      bl[t] = *(const bf16x8*)(Bl + boff[t]);
      aoff[t] += 32; boff[t] += 32;
    }
#pragma unroll
    for (int i = 0; i < 4; ++i)
#pragma unroll
      for (int j = 0; j < 4; ++j) {
        acc[i][j] = __builtin_amdgcn_mfma_f32_16x16x32_bf16(ah[i], bh[j], acc[i][j], 0, 0, 0);
        acc[i][j] = __builtin_amdgcn_mfma_f32_16x16x32_bf16(ah[i], bl[j], acc[i][j], 0, 0, 0);
        acc[i][j] = __builtin_amdgcn_mfma_f32_16x16x32_bf16(al[i], bh[j], acc[i][j], 0, 0, 0);
      }
  }
#pragma unroll
  for (int i = 0; i < 4; ++i) {
#pragma unroll
    for (int r = 0; r < 4; ++r) {
      int row = m0 + i * 16 + l16 * 4 + r;
      if (row >= M) continue;
#pragma unroll
      for (int j = 0; j < 4; ++j) {
        int col = n0 + j * 16 + l15;
        float v = acc[i][j][r];
        if (OUT16) ((__half*)Cout)[(size_t)row * DD + col] = __float2half(v);
        else       ((float*)Cout)[(size_t)row * DD + col] = v;
      }
    }
  }
}

// ---------------- fp32 tiled GEMM 64x64 (MLP head) ----------------
// mode: 1 = +bias, 2 = +bias then exact GELU
__global__ __launch_bounds__(256) void k_gemm(const float* __restrict__ A, const float* __restrict__ B,
                                              float* __restrict__ Cout, const float* __restrict__ bias,
                                              int M, int Nc, int K, int mode) {
  __shared__ float As[16][68];
  __shared__ float Bs[16][68];
  int tid = threadIdx.x;
  int m0 = blockIdx.x * 64, n0 = blockIdx.y * 64;
  int tx = tid & 15, ty = tid >> 4;
  int lam = tid >> 2, lak = (tid & 3) * 4;
  int lbk = tid >> 4, lbn = (tid & 15) * 4;
  float acc[4][4] = {};
  int ar = m0 + lam;
  for (int k0 = 0; k0 < K; k0 += 16) {
    float4 av;
    if (ar < M) av = *(const float4*)(A + (size_t)ar * K + k0 + lak);
    else        av = make_float4(0.f, 0.f, 0.f, 0.f);
    As[lak + 0][lam] = av.x; As[lak + 1][lam] = av.y;
    As[lak + 2][lam] = av.z; As[lak + 3][lam] = av.w;
    *(float4*)&Bs[lbk][lbn] = *(const float4*)(B + (size_t)(k0 + lbk) * Nc + n0 + lbn);
    __syncthreads();
#pragma unroll
    for (int kk = 0; kk < 16; ++kk) {
      const float4 a4 = *(const float4*)&As[kk][ty << 2];
      const float4 b4 = *(const float4*)&Bs[kk][tx << 2];
      const float a[4] = {a4.x, a4.y, a4.z, a4.w};
      const float b[4] = {b4.x, b4.y, b4.z, b4.w};
#pragma unroll
      for (int i = 0; i < 4; ++i)
#pragma unroll
        for (int j = 0; j < 4; ++j)
          acc[i][j] = fmaf(a[i], b[j], acc[i][j]);
    }
    __syncthreads();
  }
#pragma unroll
  for (int i = 0; i < 4; ++i) {
    int row = m0 + ty * 4 + i;
    if (row >= M) continue;
#pragma unroll
    for (int j = 0; j < 4; ++j) {
      int col = n0 + tx * 4 + j;
      float v = acc[i][j] + bias[col];
      if (mode == 2) v = 0.5f * v * (1.0f + erff(v * 0.70710678118654752f));
      Cout[(size_t)row * Nc + col] = v;
    }
  }
}

// ---------------- attention score dots from fp16 xp: s_src/s_dst [N,4] ----------------
__global__ __launch_bounds__(256) void k_sdots(const __half* __restrict__ xp16,
                                               const float* __restrict__ asw,
                                               const float* __restrict__ adw,
                                               float* __restrict__ ssrc, float* __restrict__ sdst) {
  int wv = threadIdx.x >> 6, ln = threadIdx.x & 63;
  int n = blockIdx.x * 4 + wv;
  int h = ln >> 4, c0 = (ln & 15) * 8;
  uint4 raw = *(const uint4*)(xp16 + (size_t)n * DD + h * 128 + c0);
  const __half2* hp = (const __half2*)&raw;
  float a = 0.f, b = 0.f;
#pragma unroll
  for (int j = 0; j < 4; ++j) {
    float2 f = __half22float2(hp[j]);
    a += f.x * asw[h * 128 + c0 + 2 * j]     + f.y * asw[h * 128 + c0 + 2 * j + 1];
    b += f.x * adw[h * 128 + c0 + 2 * j]     + f.y * adw[h * 128 + c0 + 2 * j + 1];
  }
#pragma unroll
  for (int o = 8; o; o >>= 1) { a += __shfl_xor(a, o); b += __shfl_xor(b, o); }
  if ((ln & 15) == 0) { ssrc[n * 4 + h] = a; sdst[n * 4 + h] = b; }
}

// ---------------- gather src scores into CSR edge order ----------------
__global__ __launch_bounds__(256) void k_escore(const int* __restrict__ csrc,
                                                const float* __restrict__ ssrc,
                                                float4* __restrict__ ez) {
  for (int k = blockIdx.x * 256 + threadIdx.x; k < ET; k += gridDim.x * 256)
    ez[k] = *(const float4*)(ssrc + (size_t)csrc[k] * 4);
}

__device__ __forceinline__ void acc8(float* acc, float w, const uint4& r) {
  const __half2* hp = (const __half2*)&r;
#pragma unroll
  for (int j = 0; j < 4; ++j) {
    float2 f = __half22float2(hp[j]);
    acc[2 * j]     += w * f.x;
    acc[2 * j + 1] += w * f.y;
  }
}

// ---------------- wave-per-node edge-softmax aggregation (fp16 gather) ----------------
__global__ __launch_bounds__(256) void k_agg(const __half* __restrict__ xp16,
                                             const float4* __restrict__ ez,
                                             const float* __restrict__ sdst,
                                             const int* __restrict__ off,
                                             const int* __restrict__ csr,
                                             const int* __restrict__ batch,
                                             const float* __restrict__ bias,
                                             float* __restrict__ xio,   // in: residual, out: pre-LN
                                             float* __restrict__ gsum, float* __restrict__ gsq) {
  int wv = threadIdx.x >> 6, ln = threadIdx.x & 63;
  int n = blockIdx.x * 4 + wv;         // NN % 4 == 0
  int beg = off[n], end = off[n + 1];
  int h = ln >> 4;

  float4 sd4 = *(const float4*)(sdst + (size_t)n * 4);
  float sdv[4] = {sd4.x, sd4.y, sd4.z, sd4.w};

  // ---- stage 1: per-head softmax max & denom over coalesced ez ----
  float m[4] = {-INFINITY, -INFINITY, -INFINITY, -INFINITY};
  float s[4] = {0.f, 0.f, 0.f, 0.f};
  for (int k = beg + ln; k < end; k += 64) {
    float4 ev4 = ez[k];
    float ev[4] = {ev4.x, ev4.y, ev4.z, ev4.w};
#pragma unroll
    for (int hh = 0; hh < 4; ++hh) {
      float e = ev[hh] + sdv[hh];
      e = (e > 0.f) ? e : 0.2f * e;
      float nm = fmaxf(m[hh], e);
      s[hh] = s[hh] * __expf(m[hh] - nm) + __expf(e - nm);
      m[hh] = nm;
    }
  }
#pragma unroll
  for (int o = 32; o; o >>= 1) {
#pragma unroll
    for (int hh = 0; hh < 4; ++hh) {
      float om = __shfl_xor(m[hh], o);
      float os = __shfl_xor(s[hh], o);
      float M = fmaxf(m[hh], om);
      if (M > -1e37f) {
        s[hh] = s[hh] * __expf(m[hh] - M) + os * __expf(om - M);
        m[hh] = M;
      }
    }
  }
  float mh  = m[h];
  float inv = 1.0f / s[h];
  float sdh = sdv[h];
  const float* eh = ((const float*)ez) + h;

  // ---- stage 2: weighted fp16 gather-accumulate, 4-edge unroll ----
  const int d = ln * 8;
  float acc[8] = {};
  int k = beg;
  for (; k + 4 <= end; k += 4) {
    int s0 = csr[k], s1 = csr[k + 1], s2 = csr[k + 2], s3 = csr[k + 3];
    uint4 r0 = *(const uint4*)(xp16 + (size_t)s0 * DD + d);
    uint4 r1 = *(const uint4*)(xp16 + (size_t)s1 * DD + d);
    uint4 r2 = *(const uint4*)(xp16 + (size_t)s2 * DD + d);
    uint4 r3 = *(const uint4*)(xp16 + (size_t)s3 * DD + d);
    float e0 = eh[4 * k]       + sdh;
    float e1 = eh[4 * (k + 1)] + sdh;
    float e2 = eh[4 * (k + 2)] + sdh;
    float e3 = eh[4 * (k + 3)] + sdh;
    e0 = (e0 > 0.f) ? e0 : 0.2f * e0;
    e1 = (e1 > 0.f) ? e1 : 0.2f * e1;
    e2 = (e2 > 0.f) ? e2 : 0.2f * e2;
    e3 = (e3 > 0.f) ? e3 : 0.2f * e3;
    acc8(acc, __expf(e0 - mh), r0);
    acc8(acc, __expf(e1 - mh), r1);
    acc8(acc, __expf(e2 - mh), r2);
    acc8(acc, __expf(e3 - mh), r3);
  }
  for (; k < end; ++k) {
    int sk = csr[k];
    uint4 r = *(const uint4*)(xp16 + (size_t)sk * DD + d);
    float e = eh[4 * k] + sdh;
    e = (e > 0.f) ? e : 0.2f * e;
    acc8(acc, __expf(e - mh), r);
  }

  // ---- epilogue: alpha-normalize, +bias, +residual, write, LN partials ----
  float4 b0 = *(const float4*)(bias + d);
  float4 b1 = *(const float4*)(bias + d + 4);
  float4 r0v = *(const float4*)(xio + (size_t)n * DD + d);
  float4 r1v = *(const float4*)(xio + (size_t)n * DD + d + 4);
  float bv[8] = {b0.x,b0.y,b0.z,b0.w,b1.x,b1.y,b1.z,b1.w};
  float rv[8] = {r0v.x,r0v.y,r0v.z,r0v.w,r1v.x,r1v.y,r1v.z,r1v.w};
  float o[8];
  float ps = 0.f, pq = 0.f;
#pragma unroll
  for (int i = 0; i < 8; ++i) {
    o[i] = acc[i] * inv + bv[i] + rv[i];
    ps += o[i];
    pq += o[i] * o[i];
  }
  *(float4*)(xio + (size_t)n * DD + d)     = make_float4(o[0], o[1], o[2], o[3]);
  *(float4*)(xio + (size_t)n * DD + d + 4) = make_float4(o[4], o[5], o[6], o[7]);
#pragma unroll
  for (int oo = 32; oo; oo >>= 1) { ps += __shfl_xor(ps, oo); pq += __shfl_xor(pq, oo); }
  if (ln == 0) {
    int g = batch[n];
    atomicAdd(&gsum[g], ps);
    atomicAdd(&gsq[g], pq);
  }
}

// ---------------- per-graph LN stats ----------------
__global__ void k_stats(const int* __restrict__ gcnt, const float* __restrict__ gsum,
                        const float* __restrict__ gsq, float* __restrict__ gmu, float* __restrict__ grstd) {
  int t = threadIdx.x;
  if (t < GG) {
    float cnt = fmaxf((float)gcnt[t] * (float)DD, 1.0f);
    float mu  = gsum[t] / cnt;
    float var = gsq[t] / cnt - mu * mu;
    var = fmaxf(var, 0.0f);
    gmu[t]   = mu;
    grstd[t] = rsqrtf(var + 1e-5f);
  }
}

// ---------------- graph-LN normalize + optional bf16 hi/lo split write ----------------
__global__ __launch_bounds__(256) void k_norm(float* __restrict__ x, const int* __restrict__ batch,
                                              const float* __restrict__ gmu, const float* __restrict__ grstd,
                                              const float* __restrict__ lnw, const float* __restrict__ lnb,
                                              ushort* __restrict__ xh, ushort* __restrict__ xl, int wsplit) {
  for (int i4 = blockIdx.x * 256 + threadIdx.x; i4 < NN * DD / 4; i4 += gridDim.x * 256) {
    int i = i4 * 4;
    int n = i >> 9, d = i & 511;
    int g = batch[n];
    float mu = gmu[g], rs = grstd[g];
    float4 v = *(float4*)(x + i);
    float4 w = *(const float4*)(lnw + d);
    float4 b = *(const float4*)(lnb + d);
    v.x = (v.x - mu) * rs * w.x + b.x;
    v.y = (v.y - mu) * rs * w.y + b.y;
    v.z = (v.z - mu) * rs * w.z + b.z;
    v.w = (v.w - mu) * rs * w.w + b.w;
    *(float4*)(x + i) = v;
    if (wsplit) {
      ushort4 hi, lo;
      hi.x = f2bf(v.x); lo.x = f2bf(v.x - bf2f(hi.x));
      hi.y = f2bf(v.y); lo.y = f2bf(v.y - bf2f(hi.y));
      hi.z = f2bf(v.z); lo.z = f2bf(v.z - bf2f(hi.z));
      hi.w = f2bf(v.w); lo.w = f2bf(v.w - bf2f(hi.w));
      *(ushort4*)(xh + i) = hi;
      *(ushort4*)(xl + i) = lo;
    }
  }
}

// ---------------- pooling: mean + max per graph (batch_vec sorted) ----------------
__device__ __forceinline__ int lowb(const int* a, int n, int key) {
  int lo = 0, hi = n;
  while (lo < hi) { int mid = (lo + hi) >> 1; if (a[mid] < key) lo = mid + 1; else hi = mid; }
  return lo;
}

__global__ __launch_bounds__(256) void k_pool(const float* __restrict__ x, const int* __restrict__ batch,
                                              float* __restrict__ pool) {
  int g = blockIdx.x, tid = threadIdx.x;
  __shared__ int sb, se;
  if (tid == 0) { sb = lowb(batch, NN, g); se = lowb(batch, NN, g + 1); }
  __syncthreads();
  int b = sb, e = se;
  float s0 = 0.f, s1 = 0.f, m0 = -INFINITY, m1 = -INFINITY;
  for (int n = b; n < e; ++n) {
    float v0 = x[(size_t)n * DD + tid];
    float v1 = x[(size_t)n * DD + tid + 256];
    s0 += v0; s1 += v1;
    m0 = fmaxf(m0, v0); m1 = fmaxf(m1, v1);
  }
  int cnt = e - b;
  float inv = 1.0f / (float)(cnt > 0 ? cnt : 1);
  pool[(size_t)g * 1024 + tid]             = s0 * inv;
  pool[(size_t)g * 1024 + tid + 256]       = s1 * inv;
  pool[(size_t)g * 1024 + 512 + tid]       = (cnt > 0) ? m0 : 0.f;
  pool[(size_t)g * 1024 + 512 + tid + 256] = (cnt > 0) ? m1 : 0.f;
}

// ---------------- final row L2 normalize ----------------
__global__ __launch_bounds__(256) void k_l2(float* __restrict__ h) {
  int g = blockIdx.x, t = threadIdx.x;
  float v = h[(size_t)g * OUTD + t];
  float q = v * v;
#pragma unroll
  for (int o = 32; o; o >>= 1) q += __shfl_xor(q, o);
  __shared__ float w[4];
  int wv = t >> 6, ln = t & 63;
  if (ln == 0) w[wv] = q;
  __syncthreads();
  float tot = w[0] + w[1] + w[2] + w[3];
  float nrm = fmaxf(sqrtf(tot), 1e-12f);
  h[(size_t)g * OUTD + t] = v / nrm;
}

// ---------------- launcher ----------------
extern "C" void kernel_launch(void* const* d_in, const int* in_sizes, int n_in,
                              void* d_out, int out_size, void* d_ws, size_t ws_size,
                              hipStream_t stream) {
  const int*   node_ids = (const int*)d_in[0];
  const int*   ei       = (const int*)d_in[1];
  const int*   batch    = (const int*)d_in[2];
  const float* emb      = (const float*)d_in[3];
  const float* W[4]  = {(const float*)d_in[4],  (const float*)d_in[10], (const float*)d_in[16], (const float*)d_in[22]};
  const float* AS[4] = {(const float*)d_in[5],  (const float*)d_in[11], (const float*)d_in[17], (const float*)d_in[23]};
  const float* AD[4] = {(const float*)d_in[6],  (const float*)d_in[12], (const float*)d_in[18], (const float*)d_in[24]};
  const float* BV[4] = {(const float*)d_in[7],  (const float*)d_in[13], (const float*)d_in[19], (const float*)d_in[25]};
  const float* LW[4] = {(const float*)d_in[8],  (const float*)d_in[14], (const float*)d_in[20], (const float*)d_in[26]};
  const float* LB[4] = {(const float*)d_in[9],  (const float*)d_in[15], (const float*)d_in[21], (const float*)d_in[27]};
  const float* res_w0 = (const float*)d_in[28];
  const float* p1w    = (const float*)d_in[29];
  const float* p1b    = (const float*)d_in[30];
  const float* p2w    = (const float*)d_in[31];
  const float* p2b    = (const float*)d_in[32];
  float* out = (float*)d_out;

  char* ws = (char*)d_ws;
  size_t pos = 0;
  auto alloc = [&](size_t bytes) -> char* {
    char* p = ws + pos;
    pos = (pos + bytes + 255) & ~size_t(255);
    return p;
  };
  float*  xb    = (float*)alloc((size_t)NN * DD * 4);
  ushort* xbh   = (ushort*)alloc((size_t)NN * DD * 2);   // also hosts x0h (20000x64) early
  ushort* xbl   = (ushort*)alloc((size_t)NN * DD * 2);   // also hosts x0l
  __half* xp16  = (__half*)alloc((size_t)NN * DD * 2);
  float*  ssrc  = (float*)alloc((size_t)NN * 4 * 4);
  float*  sdst  = (float*)alloc((size_t)NN * 4 * 4);
  int*    coff  = (int*)alloc((size_t)(NN + 1) * 4);
  int*    ccur  = (int*)alloc((size_t)NN * 4);
  int*    csrc  = (int*)alloc((size_t)ET * 4);
  int*    gcnt  = (int*)alloc((size_t)GG * 4);
  float*  gsum  = (float*)alloc((size_t)GG * 4 * 2);
  float*  gsq   = gsum + GG;
  float*  gmu   = (float*)alloc((size_t)GG * 4 * 2);
  float*  grstd = gmu + GG;
  float4* ez    = (float4*)alloc((size_t)ET * 16);
  // weight transposed hi/lo splits
  ushort* w0th = (ushort*)alloc((size_t)DEE * DD * 2); ushort* w0tl = (ushort*)alloc((size_t)DEE * DD * 2);
  ushort* rwth = (ushort*)alloc((size_t)DEE * DD * 2); ushort* rwtl = (ushort*)alloc((size_t)DEE * DD * 2);
  ushort* wth[4] = {w0th, nullptr, nullptr, nullptr};
  ushort* wtl[4] = {w0tl, nullptr, nullptr, nullptr};
  for (int i = 1; i < 4; ++i) {
    wth[i] = (ushort*)alloc((size_t)DD * DD * 2);
    wtl[i] = (ushort*)alloc((size_t)DD * DD * 2);
  }
  // pool & h1 overlap the ez region (disjoint in time: ez dead after last k_agg)
  float* pool = (float*)ez;
  float* h1   = pool + (size_t)GG * 1024;
  (void)ws_size; (void)in_sizes; (void)n_in; (void)out_size;

  // ---- CSR + histogram + weight prep ----
  hipMemsetAsync(ccur, 0, (size_t)NN * 4, stream);
  hipMemsetAsync(gcnt, 0, (size_t)GG * 4, stream);
  k_embsplit<<<1250, 256, 0, stream>>>(node_ids, emb, xbh, xbl);   // x0 split (aliased)
  k_gcnt<<<256, 256, 0, stream>>>(batch, gcnt);
  k_count<<<1024, 256, 0, stream>>>(ei, ccur);
  k_scan<<<1, 1024, 0, stream>>>(ccur, coff);
  hipMemsetAsync(ccur, 0, (size_t)NN * 4, stream);
  k_scatter<<<1024, 256, 0, stream>>>(ei, coff, ccur, csrc);
  k_wsplitT<<<dim3(16, 2),  256, 0, stream>>>(W[0],   w0th, w0tl, DEE, DD);
  k_wsplitT<<<dim3(16, 2),  256, 0, stream>>>(res_w0, rwth, rwtl, DEE, DD);
  for (int i = 1; i < 4; ++i)
    k_wsplitT<<<dim3(16, 16), 256, 0, stream>>>(W[i], wth[i], wtl[i], DD, DD);

  // ---- L0 projections (A = x0 split, aliased in xbh/xbl) ----
  k_mfma<1><<<dim3(4, 157), 256, 0, stream>>>(xbh, xbl, w0th, w0tl, xp16, NN, DEE);
  k_mfma<0><<<dim3(4, 157), 256, 0, stream>>>(xbh, xbl, rwth, rwtl, xb,   NN, DEE);

  // ---- 4 GAT layers ----
  for (int L = 0; L < 4; ++L) {
    k_sdots<<<NN / 4, 256, 0, stream>>>(xp16, AS[L], AD[L], ssrc, sdst);
    k_escore<<<1024, 256, 0, stream>>>(csrc, ssrc, ez);
    hipMemsetAsync(gsum, 0, (size_t)GG * 8, stream);
    k_agg<<<NN / 4, 256, 0, stream>>>(xp16, ez, sdst, coff, csrc, batch, BV[L], xb, gsum, gsq);
    k_stats<<<1, GG, 0, stream>>>(gcnt, gsum, gsq, gmu, grstd);
    k_norm<<<2048, 256, 0, stream>>>(xb, batch, gmu, grstd, LW[L], LB[L], xbh, xbl, (L < 3) ? 1 : 0);
    if (L < 3)
      k_mfma<1><<<dim3(4, 157), 256, 0, stream>>>(xbh, xbl, wth[L + 1], wtl[L + 1], xp16, NN, DD);
  }

  // ---- pool + MLP head + normalize ----
  k_pool<<<GG, 256, 0, stream>>>(xb, batch, pool);
  k_gemm<<<dim3(2, 16), 256, 0, stream>>>(pool, p1w, h1, p1b, GG, 1024, 1024, 2);
  k_gemm<<<dim3(2, 4), 256, 0, stream>>>(h1, p2w, out, p2b, GG, OUTD, 1024, 1);
  k_l2<<<GG, 256, 0, stream>>>(out);
}

// Round 4
// 1041.247 us; speedup vs baseline: 1.5591x; 1.2661x over previous
//
#include <hip/hip_runtime.h>
#include <hip/hip_fp16.h>
#include <math.h>

constexpr int NN   = 20000;
constexpr int EE   = 320000;
constexpr int ET   = EE + NN;   // 340000 with self loops
constexpr int GG   = 128;
constexpr int DEE  = 64;
constexpr int DD   = 512;
constexpr int OUTD = 256;

using half8 = __attribute__((ext_vector_type(8))) _Float16;
using f32x4 = __attribute__((ext_vector_type(4))) float;

// ---- async global->LDS 16B (wave-uniform LDS base + lane*16 implicit) ----
__device__ __forceinline__ void ldg2lds16(const void* g, void* l) {
  __builtin_amdgcn_global_load_lds((const __attribute__((address_space(1))) unsigned*)g,
                                   (__attribute__((address_space(3))) unsigned*)l, 16, 0, 0);
}

// ---------------- embedding gather -> f16 ----------------
__global__ __launch_bounds__(256) void k_embf16(const int* __restrict__ ids,
                                                const float* __restrict__ emb,
                                                __half* __restrict__ x0) {
  for (int i = blockIdx.x * 256 + threadIdx.x; i < NN * 16; i += gridDim.x * 256) {
    int n = i >> 4, q = (i & 15) * 4;
    float4 v = *(const float4*)(emb + (size_t)ids[n] * DEE + q);
    __half2* o = (__half2*)(x0 + (size_t)n * DEE + q);
    o[0] = __floats2half2_rn(v.x, v.y);
    o[1] = __floats2half2_rn(v.z, v.w);
  }
}

// ---------------- weight transpose + f16 hi/lo split: T[n][k] = W[k][n] ----------------
__global__ __launch_bounds__(256) void k_wsplit16T(const float* __restrict__ W,
                                                   __half* __restrict__ Th, __half* __restrict__ Tl,
                                                   int K, int N) {
  __shared__ float t[32][33];
  int n0 = blockIdx.x * 32, k0 = blockIdx.y * 32;
  int c = threadIdx.x & 31, r4 = threadIdx.x >> 5;
  for (int rr = 0; rr < 32; rr += 8)
    t[rr + r4][c] = W[(size_t)(k0 + rr + r4) * N + n0 + c];
  __syncthreads();
  for (int rr = 0; rr < 32; rr += 8) {
    int n = n0 + rr + r4, k = k0 + c;
    float v = t[c][rr + r4];
    __half hi = __float2half_rn(v);
    Th[(size_t)n * K + k] = hi;
    Tl[(size_t)n * K + k] = __float2half_rn(v - __half2float(hi));
  }
}

// ---------------- graph node-count histogram ----------------
__global__ __launch_bounds__(256) void k_gcnt(const int* __restrict__ batch, int* __restrict__ gcnt) {
  for (int n = blockIdx.x * 256 + threadIdx.x; n < NN; n += gridDim.x * 256)
    atomicAdd(&gcnt[batch[n]], 1);
}

// ---------------- CSR build ----------------
__global__ __launch_bounds__(256) void k_count(const int* __restrict__ ei, int* __restrict__ cnt) {
  for (int k = blockIdx.x * 256 + threadIdx.x; k < ET; k += gridDim.x * 256) {
    int d = (k < EE) ? ei[EE + k] : (k - EE);
    atomicAdd(&cnt[d], 1);
  }
}

__global__ __launch_bounds__(1024) void k_scan(const int* __restrict__ cnt, int* __restrict__ off) {
  __shared__ int part[1024];
  int tid = threadIdx.x;
  constexpr int CH = (NN + 1023) / 1024;  // 20
  int base = tid * CH;
  int s = 0;
  for (int i = 0; i < CH; ++i) { int idx = base + i; if (idx < NN) s += cnt[idx]; }
  part[tid] = s;
  __syncthreads();
  for (int o = 1; o < 1024; o <<= 1) {
    int add = (tid >= o) ? part[tid - o] : 0;
    int v = part[tid];
    __syncthreads();
    part[tid] = v + add;
    __syncthreads();
  }
  int run = (tid == 0) ? 0 : part[tid - 1];
  for (int i = 0; i < CH; ++i) {
    int idx = base + i;
    if (idx < NN) { off[idx] = run; run += cnt[idx]; }
  }
  if (tid == 1023) off[NN] = ET;
}

__global__ __launch_bounds__(256) void k_scatter(const int* __restrict__ ei, const int* __restrict__ off,
                                                 int* __restrict__ cur, int* __restrict__ csrc) {
  for (int k = blockIdx.x * 256 + threadIdx.x; k < ET; k += gridDim.x * 256) {
    int s = (k < EE) ? ei[k]      : (k - EE);
    int d = (k < EE) ? ei[EE + k] : (k - EE);
    int p = atomicAdd(&cur[d], 1);
    csrc[off[d] + p] = s;
  }
}

// ---------------- f16 MFMA GEMM (A single + B hi/lo split): C[M,512] = A[M,K] @ B ----------------
// A: f16 row-major [M][K]; Bh/Bl: f16 TRANSPOSED [512][K].
// LDS-staged (global_load_lds w16), XOR-swizzled slots, 128x128 tile, BK=64.
template<int OUT16>
__global__ __launch_bounds__(256) void k_mfma2(const __half* __restrict__ A,
                                               const __half* __restrict__ Bh,
                                               const __half* __restrict__ Bl,
                                               void* __restrict__ Cout, int M, int K) {
  __shared__ __half lds[3 * 128 * 64];   // A | Bh | Bl, 16 KB each
  __half* As  = lds;
  __half* Bhs = lds + 8192;
  __half* Bls = lds + 16384;
  const int tid = threadIdx.x, l = tid & 63, w = tid >> 6;
  const int wr = w >> 1, wc = w & 1;
  const int m0 = blockIdx.y * 128, n0 = blockIdx.x * 128;
  const int l15 = l & 15, l16 = l >> 4;
  const int sr = l >> 3;                 // staging sub-row 0..7
  const int ss = (l & 7) ^ sr;           // staging swizzled 16B slot

  f32x4 acc[4][4] = {};
  for (int k0 = 0; k0 < K; k0 += 64) {
    // ---- stage A, Bh, Bl: each 128 rows x 128B, 4 issues x 256 lanes x 16B ----
#pragma unroll
    for (int j = 0; j < 4; ++j) {
      int rbase = j * 32 + w * 8;
      int rl = rbase + sr;
      int gA = min(m0 + rl, M - 1);
      int gB = n0 + rl;
      const size_t ko = (size_t)(k0 + ss * 8);
      ldg2lds16(A  + (size_t)gA * K + ko, As  + rbase * 64);
      ldg2lds16(Bh + (size_t)gB * K + ko, Bhs + rbase * 64);
      ldg2lds16(Bl + (size_t)gB * K + ko, Bls + rbase * 64);
    }
    __syncthreads();
#pragma unroll
    for (int kh = 0; kh < 2; ++kh) {
      half8 af[4], bhf[4], blf[4];
#pragma unroll
      for (int t = 0; t < 4; ++t) {
        int ra = wr * 64 + t * 16 + l15;
        int ca = (kh * 4 + l16) ^ (ra & 7);
        af[t] = *(const half8*)(As + ra * 64 + ca * 8);
        int rb = wc * 64 + t * 16 + l15;
        int cb = (kh * 4 + l16) ^ (rb & 7);
        bhf[t] = *(const half8*)(Bhs + rb * 64 + cb * 8);
        blf[t] = *(const half8*)(Bls + rb * 64 + cb * 8);
      }
#pragma unroll
      for (int i = 0; i < 4; ++i)
#pragma unroll
        for (int j = 0; j < 4; ++j) {
          acc[i][j] = __builtin_amdgcn_mfma_f32_16x16x32_f16(af[i], bhf[j], acc[i][j], 0, 0, 0);
          acc[i][j] = __builtin_amdgcn_mfma_f32_16x16x32_f16(af[i], blf[j], acc[i][j], 0, 0, 0);
        }
    }
    __syncthreads();
  }
#pragma unroll
  for (int i = 0; i < 4; ++i) {
#pragma unroll
    for (int r = 0; r < 4; ++r) {
      int row = m0 + wr * 64 + i * 16 + l16 * 4 + r;
      if (row >= M) continue;
#pragma unroll
      for (int j = 0; j < 4; ++j) {
        int col = n0 + wc * 64 + j * 16 + l15;
        float v = acc[i][j][r];
        if (OUT16) ((__half*)Cout)[(size_t)row * DD + col] = __float2half(v);
        else       ((float*)Cout)[(size_t)row * DD + col]  = v;
      }
    }
  }
}

// ---------------- fp32 tiled GEMM 64x64 (MLP head) ----------------
// mode: 1 = +bias, 2 = +bias then exact GELU
__global__ __launch_bounds__(256) void k_gemm(const float* __restrict__ A, const float* __restrict__ B,
                                              float* __restrict__ Cout, const float* __restrict__ bias,
                                              int M, int Nc, int K, int mode) {
  __shared__ float As[16][68];
  __shared__ float Bs[16][68];
  int tid = threadIdx.x;
  int m0 = blockIdx.x * 64, n0 = blockIdx.y * 64;
  int tx = tid & 15, ty = tid >> 4;
  int lam = tid >> 2, lak = (tid & 3) * 4;
  int lbk = tid >> 4, lbn = (tid & 15) * 4;
  float acc[4][4] = {};
  int ar = m0 + lam;
  for (int k0 = 0; k0 < K; k0 += 16) {
    float4 av;
    if (ar < M) av = *(const float4*)(A + (size_t)ar * K + k0 + lak);
    else        av = make_float4(0.f, 0.f, 0.f, 0.f);
    As[lak + 0][lam] = av.x; As[lak + 1][lam] = av.y;
    As[lak + 2][lam] = av.z; As[lak + 3][lam] = av.w;
    *(float4*)&Bs[lbk][lbn] = *(const float4*)(B + (size_t)(k0 + lbk) * Nc + n0 + lbn);
    __syncthreads();
#pragma unroll
    for (int kk = 0; kk < 16; ++kk) {
      const float4 a4 = *(const float4*)&As[kk][ty << 2];
      const float4 b4 = *(const float4*)&Bs[kk][tx << 2];
      const float a[4] = {a4.x, a4.y, a4.z, a4.w};
      const float b[4] = {b4.x, b4.y, b4.z, b4.w};
#pragma unroll
      for (int i = 0; i < 4; ++i)
#pragma unroll
        for (int j = 0; j < 4; ++j)
          acc[i][j] = fmaf(a[i], b[j], acc[i][j]);
    }
    __syncthreads();
  }
#pragma unroll
  for (int i = 0; i < 4; ++i) {
    int row = m0 + ty * 4 + i;
    if (row >= M) continue;
#pragma unroll
    for (int j = 0; j < 4; ++j) {
      int col = n0 + tx * 4 + j;
      float v = acc[i][j] + bias[col];
      if (mode == 2) v = 0.5f * v * (1.0f + erff(v * 0.70710678118654752f));
      Cout[(size_t)row * Nc + col] = v;
    }
  }
}

// ---------------- attention score dots from fp16 xp: s_src/s_dst [N,4] ----------------
__global__ __launch_bounds__(256) void k_sdots(const __half* __restrict__ xp16,
                                               const float* __restrict__ asw,
                                               const float* __restrict__ adw,
                                               float* __restrict__ ssrc, float* __restrict__ sdst) {
  int wv = threadIdx.x >> 6, ln = threadIdx.x & 63;
  int n = blockIdx.x * 4 + wv;
  int h = ln >> 4, c0 = (ln & 15) * 8;
  uint4 raw = *(const uint4*)(xp16 + (size_t)n * DD + h * 128 + c0);
  const __half2* hp = (const __half2*)&raw;
  float a = 0.f, b = 0.f;
#pragma unroll
  for (int j = 0; j < 4; ++j) {
    float2 f = __half22float2(hp[j]);
    a += f.x * asw[h * 128 + c0 + 2 * j]     + f.y * asw[h * 128 + c0 + 2 * j + 1];
    b += f.x * adw[h * 128 + c0 + 2 * j]     + f.y * adw[h * 128 + c0 + 2 * j + 1];
  }
#pragma unroll
  for (int o = 8; o; o >>= 1) { a += __shfl_xor(a, o); b += __shfl_xor(b, o); }
  if ((ln & 15) == 0) { ssrc[n * 4 + h] = a; sdst[n * 4 + h] = b; }
}

// ---------------- gather src scores into CSR edge order ----------------
__global__ __launch_bounds__(256) void k_escore(const int* __restrict__ csrc,
                                                const float* __restrict__ ssrc,
                                                float4* __restrict__ ez) {
  for (int k = blockIdx.x * 256 + threadIdx.x; k < ET; k += gridDim.x * 256)
    ez[k] = *(const float4*)(ssrc + (size_t)csrc[k] * 4);
}

__device__ __forceinline__ void acc8(float* acc, float w, const uint4& r) {
  const __half2* hp = (const __half2*)&r;
#pragma unroll
  for (int j = 0; j < 4; ++j) {
    float2 f = __half22float2(hp[j]);
    acc[2 * j]     += w * f.x;
    acc[2 * j + 1] += w * f.y;
  }
}

// ---------------- wave-per-node edge-softmax aggregation (fp16 gather) ----------------
__global__ __launch_bounds__(256) void k_agg(const __half* __restrict__ xp16,
                                             const float4* __restrict__ ez,
                                             const float* __restrict__ sdst,
                                             const int* __restrict__ off,
                                             const int* __restrict__ csr,
                                             const int* __restrict__ batch,
                                             const float* __restrict__ bias,
                                             float* __restrict__ xio,   // in: residual, out: pre-LN
                                             float* __restrict__ gsum, float* __restrict__ gsq) {
  int wv = threadIdx.x >> 6, ln = threadIdx.x & 63;
  int n = blockIdx.x * 4 + wv;         // NN % 4 == 0
  int beg = off[n], end = off[n + 1];
  int h = ln >> 4;

  float4 sd4 = *(const float4*)(sdst + (size_t)n * 4);
  float sdv[4] = {sd4.x, sd4.y, sd4.z, sd4.w};

  // ---- stage 1: per-head softmax max & denom over coalesced ez ----
  float m[4] = {-INFINITY, -INFINITY, -INFINITY, -INFINITY};
  float s[4] = {0.f, 0.f, 0.f, 0.f};
  for (int k = beg + ln; k < end; k += 64) {
    float4 ev4 = ez[k];
    float ev[4] = {ev4.x, ev4.y, ev4.z, ev4.w};
#pragma unroll
    for (int hh = 0; hh < 4; ++hh) {
      float e = ev[hh] + sdv[hh];
      e = (e > 0.f) ? e : 0.2f * e;
      float nm = fmaxf(m[hh], e);
      s[hh] = s[hh] * __expf(m[hh] - nm) + __expf(e - nm);
      m[hh] = nm;
    }
  }
#pragma unroll
  for (int o = 32; o; o >>= 1) {
#pragma unroll
    for (int hh = 0; hh < 4; ++hh) {
      float om = __shfl_xor(m[hh], o);
      float os = __shfl_xor(s[hh], o);
      float M = fmaxf(m[hh], om);
      if (M > -1e37f) {
        s[hh] = s[hh] * __expf(m[hh] - M) + os * __expf(om - M);
        m[hh] = M;
      }
    }
  }
  float mh  = m[h];
  float inv = 1.0f / s[h];
  float sdh = sdv[h];
  const float* eh = ((const float*)ez) + h;

  // ---- stage 2: weighted fp16 gather-accumulate, 4-edge unroll ----
  const int d = ln * 8;
  float acc[8] = {};
  int k = beg;
  for (; k + 4 <= end; k += 4) {
    int s0 = csr[k], s1 = csr[k + 1], s2 = csr[k + 2], s3 = csr[k + 3];
    uint4 r0 = *(const uint4*)(xp16 + (size_t)s0 * DD + d);
    uint4 r1 = *(const uint4*)(xp16 + (size_t)s1 * DD + d);
    uint4 r2 = *(const uint4*)(xp16 + (size_t)s2 * DD + d);
    uint4 r3 = *(const uint4*)(xp16 + (size_t)s3 * DD + d);
    float e0 = eh[4 * k]       + sdh;
    float e1 = eh[4 * (k + 1)] + sdh;
    float e2 = eh[4 * (k + 2)] + sdh;
    float e3 = eh[4 * (k + 3)] + sdh;
    e0 = (e0 > 0.f) ? e0 : 0.2f * e0;
    e1 = (e1 > 0.f) ? e1 : 0.2f * e1;
    e2 = (e2 > 0.f) ? e2 : 0.2f * e2;
    e3 = (e3 > 0.f) ? e3 : 0.2f * e3;
    acc8(acc, __expf(e0 - mh), r0);
    acc8(acc, __expf(e1 - mh), r1);
    acc8(acc, __expf(e2 - mh), r2);
    acc8(acc, __expf(e3 - mh), r3);
  }
  for (; k < end; ++k) {
    int sk = csr[k];
    uint4 r = *(const uint4*)(xp16 + (size_t)sk * DD + d);
    float e = eh[4 * k] + sdh;
    e = (e > 0.f) ? e : 0.2f * e;
    acc8(acc, __expf(e - mh), r);
  }

  // ---- epilogue: alpha-normalize, +bias, +residual, write, LN partials ----
  float4 b0 = *(const float4*)(bias + d);
  float4 b1 = *(const float4*)(bias + d + 4);
  float4 r0v = *(const float4*)(xio + (size_t)n * DD + d);
  float4 r1v = *(const float4*)(xio + (size_t)n * DD + d + 4);
  float bv[8] = {b0.x,b0.y,b0.z,b0.w,b1.x,b1.y,b1.z,b1.w};
  float rv[8] = {r0v.x,r0v.y,r0v.z,r0v.w,r1v.x,r1v.y,r1v.z,r1v.w};
  float o[8];
  float ps = 0.f, pq = 0.f;
#pragma unroll
  for (int i = 0; i < 8; ++i) {
    o[i] = acc[i] * inv + bv[i] + rv[i];
    ps += o[i];
    pq += o[i] * o[i];
  }
  *(float4*)(xio + (size_t)n * DD + d)     = make_float4(o[0], o[1], o[2], o[3]);
  *(float4*)(xio + (size_t)n * DD + d + 4) = make_float4(o[4], o[5], o[6], o[7]);
#pragma unroll
  for (int oo = 32; oo; oo >>= 1) { ps += __shfl_xor(ps, oo); pq += __shfl_xor(pq, oo); }
  if (ln == 0) {
    int g = batch[n];
    atomicAdd(&gsum[g], ps);
    atomicAdd(&gsq[g], pq);
  }
}

// ---------------- per-graph LN stats ----------------
__global__ void k_stats(const int* __restrict__ gcnt, const float* __restrict__ gsum,
                        const float* __restrict__ gsq, float* __restrict__ gmu, float* __restrict__ grstd) {
  int t = threadIdx.x;
  if (t < GG) {
    float cnt = fmaxf((float)gcnt[t] * (float)DD, 1.0f);
    float mu  = gsum[t] / cnt;
    float var = gsq[t] / cnt - mu * mu;
    var = fmaxf(var, 0.0f);
    gmu[t]   = mu;
    grstd[t] = rsqrtf(var + 1e-5f);
  }
}

// ---------------- graph-LN normalize + optional f16 write (next GEMM's A) ----------------
__global__ __launch_bounds__(256) void k_norm(float* __restrict__ x, const int* __restrict__ batch,
                                              const float* __restrict__ gmu, const float* __restrict__ grstd,
                                              const float* __restrict__ lnw, const float* __restrict__ lnb,
                                              __half* __restrict__ xh, int wf16) {
  for (int i4 = blockIdx.x * 256 + threadIdx.x; i4 < NN * DD / 4; i4 += gridDim.x * 256) {
    int i = i4 * 4;
    int n = i >> 9, d = i & 511;
    int g = batch[n];
    float mu = gmu[g], rs = grstd[g];
    float4 v = *(float4*)(x + i);
    float4 w = *(const float4*)(lnw + d);
    float4 b = *(const float4*)(lnb + d);
    v.x = (v.x - mu) * rs * w.x + b.x;
    v.y = (v.y - mu) * rs * w.y + b.y;
    v.z = (v.z - mu) * rs * w.z + b.z;
    v.w = (v.w - mu) * rs * w.w + b.w;
    *(float4*)(x + i) = v;
    if (wf16) {
      __half2* o = (__half2*)(xh + i);
      o[0] = __floats2half2_rn(v.x, v.y);
      o[1] = __floats2half2_rn(v.z, v.w);
    }
  }
}

// ---------------- pooling: mean + max per graph (batch_vec sorted) ----------------
__device__ __forceinline__ int lowb(const int* a, int n, int key) {
  int lo = 0, hi = n;
  while (lo < hi) { int mid = (lo + hi) >> 1; if (a[mid] < key) lo = mid + 1; else hi = mid; }
  return lo;
}

__global__ __launch_bounds__(256) void k_pool(const float* __restrict__ x, const int* __restrict__ batch,
                                              float* __restrict__ pool) {
  int g = blockIdx.x, tid = threadIdx.x;
  __shared__ int sb, se;
  if (tid == 0) { sb = lowb(batch, NN, g); se = lowb(batch, NN, g + 1); }
  __syncthreads();
  int b = sb, e = se;
  float s0 = 0.f, s1 = 0.f, m0 = -INFINITY, m1 = -INFINITY;
  for (int n = b; n < e; ++n) {
    float v0 = x[(size_t)n * DD + tid];
    float v1 = x[(size_t)n * DD + tid + 256];
    s0 += v0; s1 += v1;
    m0 = fmaxf(m0, v0); m1 = fmaxf(m1, v1);
  }
  int cnt = e - b;
  float inv = 1.0f / (float)(cnt > 0 ? cnt : 1);
  pool[(size_t)g * 1024 + tid]             = s0 * inv;
  pool[(size_t)g * 1024 + tid + 256]       = s1 * inv;
  pool[(size_t)g * 1024 + 512 + tid]       = (cnt > 0) ? m0 : 0.f;
  pool[(size_t)g * 1024 + 512 + tid + 256] = (cnt > 0) ? m1 : 0.f;
}

// ---------------- final row L2 normalize ----------------
__global__ __launch_bounds__(256) void k_l2(float* __restrict__ h) {
  int g = blockIdx.x, t = threadIdx.x;
  float v = h[(size_t)g * OUTD + t];
  float q = v * v;
#pragma unroll
  for (int o = 32; o; o >>= 1) q += __shfl_xor(q, o);
  __shared__ float w[4];
  int wv = t >> 6, ln = t & 63;
  if (ln == 0) w[wv] = q;
  __syncthreads();
  float tot = w[0] + w[1] + w[2] + w[3];
  float nrm = fmaxf(sqrtf(tot), 1e-12f);
  h[(size_t)g * OUTD + t] = v / nrm;
}

// ---------------- launcher ----------------
extern "C" void kernel_launch(void* const* d_in, const int* in_sizes, int n_in,
                              void* d_out, int out_size, void* d_ws, size_t ws_size,
                              hipStream_t stream) {
  const int*   node_ids = (const int*)d_in[0];
  const int*   ei       = (const int*)d_in[1];
  const int*   batch    = (const int*)d_in[2];
  const float* emb      = (const float*)d_in[3];
  const float* W[4]  = {(const float*)d_in[4],  (const float*)d_in[10], (const float*)d_in[16], (const float*)d_in[22]};
  const float* AS[4] = {(const float*)d_in[5],  (const float*)d_in[11], (const float*)d_in[17], (const float*)d_in[23]};
  const float* AD[4] = {(const float*)d_in[6],  (const float*)d_in[12], (const float*)d_in[18], (const float*)d_in[24]};
  const float* BV[4] = {(const float*)d_in[7],  (const float*)d_in[13], (const float*)d_in[19], (const float*)d_in[25]};
  const float* LW[4] = {(const float*)d_in[8],  (const float*)d_in[14], (const float*)d_in[20], (const float*)d_in[26]};
  const float* LB[4] = {(const float*)d_in[9],  (const float*)d_in[15], (const float*)d_in[21], (const float*)d_in[27]};
  const float* res_w0 = (const float*)d_in[28];
  const float* p1w    = (const float*)d_in[29];
  const float* p1b    = (const float*)d_in[30];
  const float* p2w    = (const float*)d_in[31];
  const float* p2b    = (const float*)d_in[32];
  float* out = (float*)d_out;

  char* ws = (char*)d_ws;
  size_t pos = 0;
  auto alloc = [&](size_t bytes) -> char* {
    char* p = ws + pos;
    pos = (pos + bytes + 255) & ~size_t(255);
    return p;
  };
  float*  xb    = (float*)alloc((size_t)NN * DD * 4);
  __half* xh16  = (__half*)alloc((size_t)NN * DD * 2);   // also hosts x0 f16 [NN][64] early
  __half* xp16  = (__half*)alloc((size_t)NN * DD * 2);
  float*  ssrc  = (float*)alloc((size_t)NN * 4 * 4);
  float*  sdst  = (float*)alloc((size_t)NN * 4 * 4);
  int*    coff  = (int*)alloc((size_t)(NN + 1) * 4);
  int*    ccur  = (int*)alloc((size_t)NN * 4);
  int*    csrc  = (int*)alloc((size_t)ET * 4);
  int*    gcnt  = (int*)alloc((size_t)GG * 4);
  float*  gsum  = (float*)alloc((size_t)GG * 4 * 2);
  float*  gsq   = gsum + GG;
  float*  gmu   = (float*)alloc((size_t)GG * 4 * 2);
  float*  grstd = gmu + GG;
  float4* ez    = (float4*)alloc((size_t)ET * 16);
  // transposed f16 hi/lo weights
  __half* w0th = (__half*)alloc((size_t)DEE * DD * 2); __half* w0tl = (__half*)alloc((size_t)DEE * DD * 2);
  __half* rwth = (__half*)alloc((size_t)DEE * DD * 2); __half* rwtl = (__half*)alloc((size_t)DEE * DD * 2);
  __half* wth[4] = {w0th, nullptr, nullptr, nullptr};
  __half* wtl[4] = {w0tl, nullptr, nullptr, nullptr};
  for (int i = 1; i < 4; ++i) {
    wth[i] = (__half*)alloc((size_t)DD * DD * 2);
    wtl[i] = (__half*)alloc((size_t)DD * DD * 2);
  }
  // pool & h1 overlap the ez region (ez dead after last k_agg)
  float* pool = (float*)ez;
  float* h1   = pool + (size_t)GG * 1024;
  (void)ws_size; (void)in_sizes; (void)n_in; (void)out_size;

  __half* x0f = xh16;   // [NN][64] f16, aliased (dead once L0 GEMMs finish)

  // ---- CSR + histogram + weight prep ----
  hipMemsetAsync(ccur, 0, (size_t)NN * 4, stream);
  hipMemsetAsync(gcnt, 0, (size_t)GG * 4, stream);
  k_embf16<<<1250, 256, 0, stream>>>(node_ids, emb, x0f);
  k_gcnt<<<256, 256, 0, stream>>>(batch, gcnt);
  k_count<<<1024, 256, 0, stream>>>(ei, ccur);
  k_scan<<<1, 1024, 0, stream>>>(ccur, coff);
  hipMemsetAsync(ccur, 0, (size_t)NN * 4, stream);
  k_scatter<<<1024, 256, 0, stream>>>(ei, coff, ccur, csrc);
  k_wsplit16T<<<dim3(16, 2),  256, 0, stream>>>(W[0],   w0th, w0tl, DEE, DD);
  k_wsplit16T<<<dim3(16, 2),  256, 0, stream>>>(res_w0, rwth, rwtl, DEE, DD);
  for (int i = 1; i < 4; ++i)
    k_wsplit16T<<<dim3(16, 16), 256, 0, stream>>>(W[i], wth[i], wtl[i], DD, DD);

  // ---- L0 projections ----
  k_mfma2<1><<<dim3(4, 157), 256, 0, stream>>>(x0f, w0th, w0tl, xp16, NN, DEE);
  k_mfma2<0><<<dim3(4, 157), 256, 0, stream>>>(x0f, rwth, rwtl, xb,   NN, DEE);

  // ---- 4 GAT layers ----
  for (int L = 0; L < 4; ++L) {
    k_sdots<<<NN / 4, 256, 0, stream>>>(xp16, AS[L], AD[L], ssrc, sdst);
    k_escore<<<1024, 256, 0, stream>>>(csrc, ssrc, ez);
    hipMemsetAsync(gsum, 0, (size_t)GG * 8, stream);
    k_agg<<<NN / 4, 256, 0, stream>>>(xp16, ez, sdst, coff, csrc, batch, BV[L], xb, gsum, gsq);
    k_stats<<<1, GG, 0, stream>>>(gcnt, gsum, gsq, gmu, grstd);
    k_norm<<<2048, 256, 0, stream>>>(xb, batch, gmu, grstd, LW[L], LB[L], xh16, (L < 3) ? 1 : 0);
    if (L < 3)
      k_mfma2<1><<<dim3(4, 157), 256, 0, stream>>>(xh16, wth[L + 1], wtl[L + 1], xp16, NN, DD);
  }

  // ---- pool + MLP head + normalize ----
  k_pool<<<GG, 256, 0, stream>>>(xb, batch, pool);
  k_gemm<<<dim3(2, 16), 256, 0, stream>>>(pool, p1w, h1, p1b, GG, 1024, 1024, 2);
  k_gemm<<<dim3(2, 4), 256, 0, stream>>>(h1, p2w, out, p2b, GG, OUTD, 1024, 1);
  k_l2<<<GG, 256, 0, stream>>>(out);
}